// Round 1
// baseline (1381.894 us; speedup 1.0000x reference)
//
#include <hip/hip_runtime.h>
#include <stdint.h>

#define PRIME 2013265921u
#define LOGN 21
#define NN (1u << LOGN)   // 2097152

// ---------- modular arithmetic ----------
__device__ __forceinline__ uint32_t mulmod(uint32_t a, uint32_t b) {
    return (uint32_t)(((uint64_t)a * (uint64_t)b) % PRIME);
}
__device__ __forceinline__ uint32_t addmod(uint32_t a, uint32_t b) {
    uint32_t s = a + b; return (s >= PRIME) ? s - PRIME : s;
}
__device__ __forceinline__ uint32_t submod(uint32_t a, uint32_t b) {
    return (a >= b) ? (a - b) : (a + PRIME - b);
}
// Shoup multiplication: w < P, wp = floor(w * 2^32 / P). Result = v*w mod P.
__device__ __forceinline__ uint32_t mulmod_shoup(uint32_t v, uint32_t w, uint32_t wp) {
    uint32_t q = __umulhi(v, wp);
    uint32_t r = v * w - q * PRIME;   // mod 2^32; true value < 2P
    return (r >= PRIME) ? r - PRIME : r;
}
__device__ uint32_t powmod(uint32_t b, uint64_t e) {
    uint32_t r = 1u;
    while (e) {
        if (e & 1ull) r = mulmod(r, b);
        b = mulmod(b, b);
        e >>= 1;
    }
    return r;
}

// ---------- twiddle table: T[k] = iroot^k, Tp[k] = floor(T[k]*2^32/P), k < 2^20 ----------
__global__ void twiddle_kernel(uint32_t* __restrict__ T, uint32_t* __restrict__ Tp) {
    uint32_t k = blockIdx.x * blockDim.x + threadIdx.x;   // < 2^20
    uint32_t root  = powmod(31u, (PRIME - 1) / NN);       // order N
    uint32_t iroot = powmod(root, PRIME - 2);
    uint32_t w = powmod(iroot, k);
    T[k]  = w;
    Tp[k] = (uint32_t)((((uint64_t)w) << 32) / PRIME);
}

// ---------- elementwise compress ----------
__global__ void compress_kernel(const int* __restrict__ wl, const int* __restrict__ wr,
                                const int* __restrict__ wo, const int* __restrict__ w4,
                                const int* __restrict__ t1, const int* __restrict__ t2,
                                const int* __restrict__ t3, const int* __restrict__ t4,
                                const int* __restrict__ q,  const int* __restrict__ zp,
                                uint32_t* __restrict__ tcomp, uint32_t* __restrict__ fcomp) {
    uint32_t i = blockIdx.x * blockDim.x + threadIdx.x;
    if (i >= NN) return;
    uint32_t z1 = ((uint32_t)zp[0]) % PRIME;
    uint32_t z2 = mulmod(z1, z1);
    uint32_t z3 = mulmod(z2, z1);
    uint32_t t = addmod(addmod((uint32_t)t1[i], mulmod((uint32_t)t2[i], z1)),
                        addmod(mulmod((uint32_t)t3[i], z2), mulmod((uint32_t)t4[i], z3)));
    uint32_t w = addmod(addmod((uint32_t)wl[i], mulmod((uint32_t)wr[i], z1)),
                        addmod(mulmod((uint32_t)wo[i], z2), mulmod((uint32_t)w4[i], z3)));
    tcomp[i] = t;
    fcomp[i] = (q[i] != 0) ? w : t;
}

// ---------- sort: bucket histogram / scan / scatter / per-bucket bitonic ----------
#define NBUCK 8192

__global__ void hist_kernel(const uint32_t* __restrict__ tcomp, const uint32_t* __restrict__ fcomp,
                            unsigned int* __restrict__ hist) {
    uint32_t total = 2u * NN;
    for (uint32_t i = blockIdx.x * blockDim.x + threadIdx.x; i < total; i += gridDim.x * blockDim.x) {
        uint32_t v = (i < NN) ? tcomp[i] : fcomp[i - NN];
        atomicAdd(&hist[v >> 18], 1u);
    }
}

__global__ void scan_kernel(const unsigned int* __restrict__ hist,
                            unsigned int* __restrict__ basearr, unsigned int* __restrict__ cursor) {
    __shared__ unsigned int ls[256];
    int t = threadIdx.x;
    unsigned int local[32];
    unsigned int s = 0;
    for (int k = 0; k < 32; k++) { local[k] = hist[t * 32 + k]; s += local[k]; }
    ls[t] = s;
    __syncthreads();
    for (int off = 1; off < 256; off <<= 1) {
        unsigned int v = (t >= off) ? ls[t - off] : 0u;
        __syncthreads();
        ls[t] += v;
        __syncthreads();
    }
    unsigned int run = ls[t] - s;  // exclusive prefix
    for (int k = 0; k < 32; k++) {
        basearr[t * 32 + k] = run;
        cursor[t * 32 + k]  = run;
        run += local[k];
    }
    if (t == 255) basearr[NBUCK] = run;
}

__global__ void scatter_kernel(const uint32_t* __restrict__ tcomp, const uint32_t* __restrict__ fcomp,
                               unsigned int* __restrict__ cursor, uint32_t* __restrict__ barr) {
    uint32_t total = 2u * NN;
    for (uint32_t i = blockIdx.x * blockDim.x + threadIdx.x; i < total; i += gridDim.x * blockDim.x) {
        uint32_t v = (i < NN) ? tcomp[i] : fcomp[i - NN];
        unsigned int pos = atomicAdd(&cursor[v >> 18], 1u);
        barr[pos] = v;
    }
}

__global__ void bucket_sort_kernel(const uint32_t* __restrict__ barr, const unsigned int* __restrict__ basearr,
                                   uint32_t* __restrict__ h1, uint32_t* __restrict__ h2) {
    __shared__ uint32_t sd[4096];
    uint32_t b  = blockIdx.x;
    uint32_t lo = basearr[b], hi = basearr[b + 1];
    uint32_t n  = hi - lo;
    if (n == 0) return;
    uint32_t np = 1; while (np < n) np <<= 1;
    if (np > 4096) np = 4096;   // unreachable for this distribution
    for (uint32_t i = threadIdx.x; i < np; i += blockDim.x)
        sd[i] = (i < n) ? barr[lo + i] : 0xFFFFFFFFu;
    __syncthreads();
    for (uint32_t k = 2; k <= np; k <<= 1) {
        for (uint32_t j = k >> 1; j > 0; j >>= 1) {
            for (uint32_t i = threadIdx.x; i < np; i += blockDim.x) {
                uint32_t ixj = i ^ j;
                if (ixj > i) {
                    uint32_t a = sd[i], c = sd[ixj];
                    bool up = ((i & k) == 0);
                    if ((a > c) == up) { sd[i] = c; sd[ixj] = a; }
                }
            }
            __syncthreads();
        }
    }
    for (uint32_t i = threadIdx.x; i < n; i += blockDim.x) {
        uint32_t p = lo + i, v = sd[i];
        if (p & 1) h2[p >> 1] = v; else h1[p >> 1] = v;
    }
}

// ---------- bit-reversal permute: dst[i] = src[rev21(i)], tiled ----------
struct SrcPtrs { const uint32_t* p[8]; };

__global__ void bitrev_kernel(SrcPtrs srcs, uint32_t* __restrict__ dst) {
    __shared__ uint32_t tile[64 * 65];
    uint32_t poly = blockIdx.y;
    const uint32_t* src = srcs.p[poly];
    uint32_t* out = dst + (size_t)poly * NN;
    uint32_t m  = blockIdx.x;                 // 9-bit middle
    uint32_t rm = __brev(m) >> 23;            // rev9
    for (uint32_t l = threadIdx.x; l < 4096; l += blockDim.x) {
        uint32_t u = l >> 6, v = l & 63;
        tile[u * 65 + v] = src[(u << 15) | (rm << 6) | v];
    }
    __syncthreads();
    for (uint32_t l = threadIdx.x; l < 4096; l += blockDim.x) {
        uint32_t a = l >> 6, b = l & 63;
        uint32_t ra = __brev(a) >> 26, rb = __brev(b) >> 26;  // rev6
        out[(a << 15) | (m << 6) | b] = tile[rb * 65 + ra];
    }
}

// ---------- NTT stages 1..12 (contiguous 4096-element chunks in LDS) ----------
__global__ void ntt_phase1_kernel(uint32_t* __restrict__ polys,
                                  const uint32_t* __restrict__ T, const uint32_t* __restrict__ Tp) {
    __shared__ uint32_t sd[4096];
    uint32_t* x = polys + (size_t)blockIdx.y * NN + (size_t)blockIdx.x * 4096;
    for (uint32_t l = threadIdx.x; l < 4096; l += blockDim.x) sd[l] = x[l];
    __syncthreads();
    for (int st = 1; st <= 12; st++) {
        uint32_t half = 1u << (st - 1);
        for (uint32_t bf = threadIdx.x; bf < 2048; bf += blockDim.x) {
            uint32_t j  = bf & (half - 1);
            uint32_t g  = bf >> (st - 1);
            uint32_t i0 = (g << st) + j, i1 = i0 + half;
            uint32_t ti = j << (LOGN - st);
            uint32_t w = T[ti], wp = Tp[ti];
            uint32_t u = sd[i0];
            uint32_t v = mulmod_shoup(sd[i1], w, wp);
            sd[i0] = addmod(u, v);
            sd[i1] = submod(u, v);
        }
        __syncthreads();
    }
    for (uint32_t l = threadIdx.x; l < 4096; l += blockDim.x) x[l] = sd[l];
}

// ---------- NTT stages 13..21 (32 cols x 512 strided rows in LDS) + n_inv ----------
__global__ void ntt_phase2_kernel(uint32_t* __restrict__ polys,
                                  const uint32_t* __restrict__ T, const uint32_t* __restrict__ Tp) {
    __shared__ uint32_t sd[16384];   // [b:512][c:32]
    uint32_t* x = polys + (size_t)blockIdx.y * NN;
    uint32_t c0 = blockIdx.x * 32;
    uint32_t ninv  = powmod(NN, PRIME - 2);
    uint32_t ninvp = (uint32_t)((((uint64_t)ninv) << 32) / PRIME);
    for (uint32_t l = threadIdx.x; l < 16384; l += blockDim.x) {
        uint32_t b = l >> 5, c = l & 31;
        sd[l] = x[c0 + c + (b << 12)];
    }
    __syncthreads();
    for (int st = 13; st <= 21; st++) {
        uint32_t hb = 1u << (st - 13);
        for (uint32_t bf = threadIdx.x; bf < 8192; bf += blockDim.x) {
            uint32_t c = bf & 31, r = bf >> 5;
            uint32_t kk = r & (hb - 1), g = r >> (st - 13);
            uint32_t b0 = (g << (st - 12)) + kk, b1 = b0 + hb;
            uint32_t j  = (c0 + c) + (kk << 12);
            uint32_t ti = j << (LOGN - st);
            uint32_t w = T[ti], wp = Tp[ti];
            uint32_t u = sd[b0 * 32 + c];
            uint32_t v = mulmod_shoup(sd[b1 * 32 + c], w, wp);
            uint32_t s0 = addmod(u, v), s1 = submod(u, v);
            if (st == 21) { s0 = mulmod_shoup(s0, ninv, ninvp); s1 = mulmod_shoup(s1, ninv, ninvp); }
            sd[b0 * 32 + c] = s0;
            sd[b1 * 32 + c] = s1;
        }
        __syncthreads();
    }
    for (uint32_t l = threadIdx.x; l < 16384; l += blockDim.x) {
        uint32_t b = l >> 5, c = l & 31;
        x[c0 + c + (b << 12)] = sd[l];
    }
}

// ---------- commits: read g once, accumulate all 8 polys x 3 comps in f64 ----------
__global__ void commit_kernel(const uint32_t* __restrict__ polys, const float* __restrict__ g,
                              double* __restrict__ dacc) {
    double acc[24];
    #pragma unroll
    for (int k = 0; k < 24; k++) acc[k] = 0.0;
    const float invp = (float)(1.0 / 2013265921.0);
    for (uint32_t i = blockIdx.x * blockDim.x + threadIdx.x; i < NN; i += gridDim.x * blockDim.x) {
        float g0 = g[i * 3 + 0], g1 = g[i * 3 + 1], g2 = g[i * 3 + 2];
        #pragma unroll
        for (int p = 0; p < 8; p++) {
            float s = (float)(int)polys[(size_t)p * NN + i] * invp;
            acc[p * 3 + 0] += (double)(s * g0);
            acc[p * 3 + 1] += (double)(s * g1);
            acc[p * 3 + 2] += (double)(s * g2);
        }
    }
    __shared__ double red[256];
    for (int k = 0; k < 24; k++) {
        red[threadIdx.x] = acc[k];
        __syncthreads();
        for (int off = 128; off > 0; off >>= 1) {
            if (threadIdx.x < off) red[threadIdx.x] += red[threadIdx.x + off];
            __syncthreads();
        }
        if (threadIdx.x == 0) atomicAdd(&dacc[k], red[0]);
        __syncthreads();
    }
}

__global__ void finalize_commits_kernel(const double* __restrict__ dacc, float* __restrict__ outf) {
    int t = threadIdx.x;
    if (t < 24) outf[t] = (float)dacc[t];
}

// ---------- convert int32 poly values (bit patterns in d_out) to float, in place ----------
__global__ void convert_kernel(float* __restrict__ outpolys) {
    uint32_t i = blockIdx.x * blockDim.x + threadIdx.x;
    if (i < 8u * NN) {
        int v = ((const int*)outpolys)[i];
        outpolys[i] = (float)v;
    }
}

extern "C" void kernel_launch(void* const* d_in, const int* in_sizes, int n_in,
                              void* d_out, int out_size, void* d_ws, size_t ws_size,
                              hipStream_t stream) {
    const int* wl = (const int*)d_in[0];
    const int* wr = (const int*)d_in[1];
    const int* wo = (const int*)d_in[2];
    const int* w4 = (const int*)d_in[3];
    const int* t1 = (const int*)d_in[4];
    const int* t2 = (const int*)d_in[5];
    const int* t3 = (const int*)d_in[6];
    const int* t4 = (const int*)d_in[7];
    const int* q  = (const int*)d_in[8];
    const float* g = (const float*)d_in[9];
    const int* zp = (const int*)d_in[10];

    char* ws = (char*)d_ws;
    uint32_t* T      = (uint32_t*)(ws);                       // 4 MB (2^20 u32)
    uint32_t* Tp     = (uint32_t*)(ws + (4ull  << 20));       // 4 MB
    uint32_t* tcomp  = (uint32_t*)(ws + (8ull  << 20));       // 8 MB
    uint32_t* fcomp  = (uint32_t*)(ws + (16ull << 20));       // 8 MB
    uint32_t* h1     = (uint32_t*)(ws + (24ull << 20));       // 8 MB
    uint32_t* h2     = (uint32_t*)(ws + (32ull << 20));       // 8 MB
    unsigned int* hist   = (unsigned int*)(ws + (40ull << 20));          // 32 KB
    unsigned int* basearr = hist + NBUCK;                                 // 8193 u32
    unsigned int* cursor  = basearr + NBUCK + 1;                          // 8192 u32
    double* dacc = (double*)(ws + (41ull << 20));                         // 192 B

    float* outf = (float*)d_out;
    uint32_t* outpolys = (uint32_t*)outf + 24;        // 8*N int32 scratch -> final floats
    uint32_t* barr = (uint32_t*)outf + 1024;          // 16 MB bucket scratch (used before NTT writes)

    hipMemsetAsync(hist, 0, NBUCK * sizeof(unsigned int), stream);
    hipMemsetAsync(dacc, 0, 24 * sizeof(double), stream);

    twiddle_kernel<<<(1u << 20) / 256, 256, 0, stream>>>(T, Tp);
    compress_kernel<<<NN / 256, 256, 0, stream>>>(wl, wr, wo, w4, t1, t2, t3, t4, q, zp, tcomp, fcomp);
    hist_kernel<<<4096, 256, 0, stream>>>(tcomp, fcomp, hist);
    scan_kernel<<<1, 256, 0, stream>>>(hist, basearr, cursor);
    scatter_kernel<<<4096, 256, 0, stream>>>(tcomp, fcomp, cursor, barr);
    bucket_sort_kernel<<<NBUCK, 256, 0, stream>>>(barr, basearr, h1, h2);

    SrcPtrs sp;
    sp.p[0] = (const uint32_t*)wl;
    sp.p[1] = (const uint32_t*)wr;
    sp.p[2] = (const uint32_t*)wo;
    sp.p[3] = (const uint32_t*)w4;
    sp.p[4] = tcomp;
    sp.p[5] = fcomp;
    sp.p[6] = h1;
    sp.p[7] = h2;
    bitrev_kernel<<<dim3(512, 8), 256, 0, stream>>>(sp, outpolys);
    ntt_phase1_kernel<<<dim3(512, 8), 256, 0, stream>>>(outpolys, T, Tp);
    ntt_phase2_kernel<<<dim3(128, 8), 256, 0, stream>>>(outpolys, T, Tp);

    commit_kernel<<<256, 256, 0, stream>>>(outpolys, g, dacc);
    finalize_commits_kernel<<<1, 64, 0, stream>>>(dacc, outf);
    convert_kernel<<<(8u * NN) / 256, 256, 0, stream>>>((float*)outpolys);
}

// Round 4
// 803.930 us; speedup vs baseline: 1.7189x; 1.7189x over previous
//
#include <hip/hip_runtime.h>
#include <stdint.h>

#define PRIME 2013265921u
#define LOGN 21
#define NN (1u << LOGN)   // 2097152

// ---------- compile-time modular helpers ----------
constexpr uint32_t cpow(uint64_t b, uint64_t e) {
    uint64_t r = 1;
    b %= PRIME;
    while (e) {
        if (e & 1ull) r = r * b % PRIME;
        b = b * b % PRIME;
        e >>= 1;
    }
    return (uint32_t)r;
}
constexpr uint32_t cpinv() {           // PRIME^{-1} mod 2^32 (Newton)
    uint32_t inv = 1;
    for (int i = 0; i < 6; i++) inv *= 2u - PRIME * inv;
    return inv;
}
constexpr uint32_t NPRIME   = (uint32_t)(0u - cpinv());            // -P^{-1} mod 2^32
constexpr uint32_t RMODP    = (uint32_t)((1ull << 32) % PRIME);    // Mont(1)
constexpr uint32_t ROOT     = cpow(31u, (PRIME - 1) / NN);
constexpr uint32_t IROOT    = cpow(ROOT, PRIME - 2);
constexpr uint32_t IROOT1K  = cpow(IROOT, 1024);
constexpr uint32_t NINV     = cpow(NN, PRIME - 2);
constexpr uint32_t NINV_M   = (uint32_t)((((uint64_t)NINV) << 32) % PRIME);  // Mont(N^-1)

// ---------- modular arithmetic ----------
__device__ __forceinline__ uint32_t addmod(uint32_t a, uint32_t b) {
    uint32_t s = a + b; return (s >= PRIME) ? s - PRIME : s;
}
__device__ __forceinline__ uint32_t submod(uint32_t a, uint32_t b) {
    return (a >= b) ? (a - b) : (a + PRIME - b);
}
__device__ __forceinline__ uint32_t mulmod(uint32_t a, uint32_t b) {
    return (uint32_t)(((uint64_t)a * (uint64_t)b) % PRIME);
}
// Montgomery: montmul(a_normal, Mont(b)) = a*b mod P (normal domain);
//             montmul(Mont(a), Mont(b)) = Mont(a*b)
__device__ __forceinline__ uint32_t montmul(uint32_t a, uint32_t b) {
    uint64_t t = (uint64_t)a * b;
    uint32_t m = (uint32_t)t * NPRIME;
    uint32_t u = (uint32_t)((t + (uint64_t)m * PRIME) >> 32);
    return (u >= PRIME) ? u - PRIME : u;
}
__device__ uint32_t powmod(uint32_t b, uint32_t e) {
    uint32_t r = 1u;
    while (e) {
        if (e & 1u) r = mulmod(r, b);
        b = mulmod(b, b);
        e >>= 1;
    }
    return r;
}
__device__ __forceinline__ uint32_t tomont(uint32_t x) {
    return (uint32_t)((((uint64_t)x) << 32) % PRIME);
}

// ---------- twiddles: A[i]=Mont(iroot^(1024 i)), B[i]=Mont(iroot^i), i<1024 ----------
__global__ void twiddle_ab_kernel(uint32_t* __restrict__ A, uint32_t* __restrict__ B) {
    uint32_t i = blockIdx.x * blockDim.x + threadIdx.x;   // < 1024
    B[i] = tomont(powmod(IROOT, i));
    A[i] = tomont(powmod(IROOT1K, i));
}
// Stage-packed table: Wfull[2^s + j] = Mont(iroot^(j << (20 - s))), j < 2^s, s=0..20
__global__ void twiddle_fill_kernel(const uint32_t* __restrict__ A, const uint32_t* __restrict__ B,
                                    uint32_t* __restrict__ Wfull) {
    uint32_t idx = blockIdx.x * blockDim.x + threadIdx.x;   // < 2^21
    if (idx == 0) { Wfull[0] = RMODP; return; }
    uint32_t s = 31u - __clz(idx);
    uint32_t j = idx ^ (1u << s);
    uint32_t e = j << (20u - s);                 // < 2^20
    Wfull[idx] = montmul(A[e >> 10], B[e & 1023u]);
}

// ---------- elementwise compress ----------
__global__ void compress_kernel(const int* __restrict__ wl, const int* __restrict__ wr,
                                const int* __restrict__ wo, const int* __restrict__ w4,
                                const int* __restrict__ t1, const int* __restrict__ t2,
                                const int* __restrict__ t3, const int* __restrict__ t4,
                                const int* __restrict__ q,  const int* __restrict__ zp,
                                uint32_t* __restrict__ tcomp, uint32_t* __restrict__ fcomp) {
    uint32_t i = blockIdx.x * blockDim.x + threadIdx.x;
    if (i >= NN) return;
    uint32_t z1 = ((uint32_t)zp[0]) % PRIME;
    uint32_t z2 = mulmod(z1, z1);
    uint32_t z3 = mulmod(z2, z1);
    uint32_t t = addmod(addmod((uint32_t)t1[i], mulmod((uint32_t)t2[i], z1)),
                        addmod(mulmod((uint32_t)t3[i], z2), mulmod((uint32_t)t4[i], z3)));
    uint32_t w = addmod(addmod((uint32_t)wl[i], mulmod((uint32_t)wr[i], z1)),
                        addmod(mulmod((uint32_t)wo[i], z2), mulmod((uint32_t)w4[i], z3)));
    tcomp[i] = t;
    fcomp[i] = (q[i] != 0) ? w : t;
}

// ---------- sort: bucket histogram / scan / scatter / per-bucket bitonic ----------
#define NBUCK 8192

__global__ void hist_kernel(const uint32_t* __restrict__ tcomp, const uint32_t* __restrict__ fcomp,
                            unsigned int* __restrict__ hist) {
    uint32_t total = 2u * NN;
    for (uint32_t i = blockIdx.x * blockDim.x + threadIdx.x; i < total; i += gridDim.x * blockDim.x) {
        uint32_t v = (i < NN) ? tcomp[i] : fcomp[i - NN];
        atomicAdd(&hist[v >> 18], 1u);
    }
}

__global__ void scan_kernel(const unsigned int* __restrict__ hist,
                            unsigned int* __restrict__ basearr, unsigned int* __restrict__ cursor) {
    __shared__ unsigned int ls[256];
    int t = threadIdx.x;
    unsigned int local[32];
    unsigned int s = 0;
    for (int k = 0; k < 32; k++) { local[k] = hist[t * 32 + k]; s += local[k]; }
    ls[t] = s;
    __syncthreads();
    for (int off = 1; off < 256; off <<= 1) {
        unsigned int v = (t >= off) ? ls[t - off] : 0u;
        __syncthreads();
        ls[t] += v;
        __syncthreads();
    }
    unsigned int run = ls[t] - s;  // exclusive prefix
    for (int k = 0; k < 32; k++) {
        basearr[t * 32 + k] = run;
        cursor[t * 32 + k]  = run;
        run += local[k];
    }
    if (t == 255) basearr[NBUCK] = run;
}

__global__ void scatter_kernel(const uint32_t* __restrict__ tcomp, const uint32_t* __restrict__ fcomp,
                               unsigned int* __restrict__ cursor, uint32_t* __restrict__ barr) {
    uint32_t total = 2u * NN;
    for (uint32_t i = blockIdx.x * blockDim.x + threadIdx.x; i < total; i += gridDim.x * blockDim.x) {
        uint32_t v = (i < NN) ? tcomp[i] : fcomp[i - NN];
        unsigned int pos = atomicAdd(&cursor[v >> 18], 1u);
        barr[pos] = v;
    }
}

__global__ void bucket_sort_kernel(const uint32_t* __restrict__ barr, const unsigned int* __restrict__ basearr,
                                   uint32_t* __restrict__ h1, uint32_t* __restrict__ h2) {
    __shared__ uint32_t sd[4096];
    uint32_t b  = blockIdx.x;
    uint32_t lo = basearr[b], hi = basearr[b + 1];
    uint32_t n  = hi - lo;
    if (n == 0) return;
    uint32_t np = 1; while (np < n) np <<= 1;
    if (np > 4096) np = 4096;   // unreachable for this distribution
    for (uint32_t i = threadIdx.x; i < np; i += blockDim.x)
        sd[i] = (i < n) ? barr[lo + i] : 0xFFFFFFFFu;
    __syncthreads();
    for (uint32_t k = 2; k <= np; k <<= 1) {
        for (uint32_t j = k >> 1; j > 0; j >>= 1) {
            for (uint32_t i = threadIdx.x; i < np; i += blockDim.x) {
                uint32_t ixj = i ^ j;
                if (ixj > i) {
                    uint32_t a = sd[i], c = sd[ixj];
                    bool up = ((i & k) == 0);
                    if ((a > c) == up) { sd[i] = c; sd[ixj] = a; }
                }
            }
            __syncthreads();
        }
    }
    for (uint32_t i = threadIdx.x; i < n; i += blockDim.x) {
        uint32_t p = lo + i, v = sd[i];
        if (p & 1) h2[p >> 1] = v; else h1[p >> 1] = v;
    }
}

// ---------- bit-reversal permute: dst[i] = src[rev21(i)], tiled ----------
struct SrcPtrs { const uint32_t* p[8]; };

__global__ void bitrev_kernel(SrcPtrs srcs, uint32_t* __restrict__ dst) {
    __shared__ uint32_t tile[64 * 65];
    uint32_t poly = blockIdx.y;
    const uint32_t* src = srcs.p[poly];
    uint32_t* out = dst + (size_t)poly * NN;
    uint32_t m  = blockIdx.x;                 // 9-bit middle
    uint32_t rm = __brev(m) >> 23;            // rev9
    for (uint32_t l = threadIdx.x; l < 4096; l += blockDim.x) {
        uint32_t u = l >> 6, v = l & 63;
        tile[u * 65 + v] = src[(u << 15) | (rm << 6) | v];
    }
    __syncthreads();
    for (uint32_t l = threadIdx.x; l < 4096; l += blockDim.x) {
        uint32_t a = l >> 6, b = l & 63;
        uint32_t ra = __brev(a) >> 26, rb = __brev(b) >> 26;  // rev6
        out[(a << 15) | (m << 6) | b] = tile[rb * 65 + ra];
    }
}

// ---------- NTT stages 1..12 in LDS; twiddles preloaded to LDS; n_inv folded in ----------
__device__ __forceinline__ uint32_t padi(uint32_t i) { return i + (i >> 5); }

__global__ __launch_bounds__(256) void ntt_phase1_kernel(uint32_t* __restrict__ polys,
                                                         const uint32_t* __restrict__ Wfull) {
    __shared__ uint32_t wt[4096];
    __shared__ uint32_t sd[4224];     // padded: i + (i>>5)
    uint32_t* x = polys + (size_t)blockIdx.y * NN + (size_t)blockIdx.x * 4096;
    for (uint32_t l = threadIdx.x; l < 4096; l += 256) {
        wt[l] = Wfull[l];
        sd[padi(l)] = x[l];
    }
    __syncthreads();
    for (int st = 1; st <= 12; st++) {
        uint32_t half = 1u << (st - 1);
        #pragma unroll 2
        for (uint32_t bf = threadIdx.x; bf < 2048; bf += 256) {
            uint32_t j  = bf & (half - 1);
            uint32_t g  = bf >> (st - 1);
            uint32_t i0 = (g << st) + j, i1 = i0 + half;
            uint32_t w = wt[half + j];
            uint32_t u = sd[padi(i0)];
            uint32_t v = montmul(sd[padi(i1)], w);
            sd[padi(i0)] = addmod(u, v);
            sd[padi(i1)] = submod(u, v);
        }
        __syncthreads();
    }
    // fold in N^-1 scaling here (linear, commutes with remaining stages)
    for (uint32_t l = threadIdx.x; l < 4096; l += 256)
        x[l] = montmul(sd[padi(l)], NINV_M);
}

// ---------- NTT stages 13..21: 16 cols x 512 rows tile; factored twiddles; 35 KiB LDS ----------
__device__ __forceinline__ uint32_t pad16(uint32_t idx) { return idx + (idx >> 5); }

__global__ __launch_bounds__(256) void ntt_phase2_kernel(uint32_t* __restrict__ polys,
                                                         const uint32_t* __restrict__ Wfull) {
    __shared__ uint32_t sd[8448];     // 8192 data + pad
    __shared__ uint32_t rowt[512];    // rowt[hb+kk] = Mont(iroot^(kk·4096 << (8-s)))
    uint32_t* x = polys + (size_t)blockIdx.y * NN;
    uint32_t c0 = blockIdx.x * 16;
    uint32_t tid = threadIdx.x;
    uint32_t c = tid & 15u;
    uint32_t rt = tid >> 4;           // 0..15

    for (uint32_t l = tid; l < 8192; l += 256) {
        uint32_t b = l >> 4, cc = l & 15;
        sd[pad16(l)] = x[c0 + cc + (b << 12)];
    }
    rowt[tid]       = (tid == 0) ? RMODP : Wfull[tid << 12];
    rowt[tid + 256] = Wfull[(uint32_t)(tid + 256) << 12];
    // per-thread column twiddles: cw[s] = Mont(iroot^((c0+c) << (8-s)))
    uint32_t cw[9];
    #pragma unroll
    for (int s = 0; s < 9; s++) cw[s] = Wfull[(1u << (12 + s)) + c0 + c];
    __syncthreads();

    #pragma unroll
    for (int s = 0; s < 9; s++) {     // stage st = 13 + s
        uint32_t hb = 1u << s;
        #pragma unroll 4
        for (uint32_t m = 0; m < 16; m++) {
            uint32_t p  = (rt << 4) + m;          // pair index 0..255
            uint32_t kk = p & (hb - 1);
            uint32_t g  = p >> s;
            uint32_t b0 = (g << (s + 1)) + kk, b1 = b0 + hb;
            uint32_t w = montmul(rowt[hb + kk], cw[s]);
            uint32_t i0 = pad16((b0 << 4) + c), i1 = pad16((b1 << 4) + c);
            uint32_t u = sd[i0];
            uint32_t v = montmul(sd[i1], w);
            sd[i0] = addmod(u, v);
            sd[i1] = submod(u, v);
        }
        __syncthreads();
    }

    for (uint32_t l = tid; l < 8192; l += 256) {
        uint32_t b = l >> 4, cc = l & 15;
        x[c0 + cc + (b << 12)] = sd[pad16(l)];
    }
}

// ---------- commits: read g once, accumulate all 8 polys x 3 comps in f64 ----------
__global__ void commit_kernel(const uint32_t* __restrict__ polys, const float* __restrict__ g,
                              double* __restrict__ dacc) {
    double acc[24];
    #pragma unroll
    for (int k = 0; k < 24; k++) acc[k] = 0.0;
    const float invp = (float)(1.0 / 2013265921.0);
    for (uint32_t i = blockIdx.x * blockDim.x + threadIdx.x; i < NN; i += gridDim.x * blockDim.x) {
        float g0 = g[i * 3 + 0], g1 = g[i * 3 + 1], g2 = g[i * 3 + 2];
        #pragma unroll
        for (int p = 0; p < 8; p++) {
            float s = (float)(int)polys[(size_t)p * NN + i] * invp;
            acc[p * 3 + 0] += (double)(s * g0);
            acc[p * 3 + 1] += (double)(s * g1);
            acc[p * 3 + 2] += (double)(s * g2);
        }
    }
    __shared__ double red[256];
    for (int k = 0; k < 24; k++) {
        red[threadIdx.x] = acc[k];
        __syncthreads();
        for (int off = 128; off > 0; off >>= 1) {
            if (threadIdx.x < off) red[threadIdx.x] += red[threadIdx.x + off];
            __syncthreads();
        }
        if (threadIdx.x == 0) atomicAdd(&dacc[k], red[0]);
        __syncthreads();
    }
}

__global__ void finalize_commits_kernel(const double* __restrict__ dacc, float* __restrict__ outf) {
    int t = threadIdx.x;
    if (t < 24) outf[t] = (float)dacc[t];
}

// ---------- convert int32 poly values (bit patterns in d_out) to float, in place ----------
__global__ void convert_kernel(float* __restrict__ outpolys) {
    uint32_t i = blockIdx.x * blockDim.x + threadIdx.x;
    if (i < 8u * NN) {
        int v = ((const int*)outpolys)[i];
        outpolys[i] = (float)v;
    }
}

extern "C" void kernel_launch(void* const* d_in, const int* in_sizes, int n_in,
                              void* d_out, int out_size, void* d_ws, size_t ws_size,
                              hipStream_t stream) {
    const int* wl = (const int*)d_in[0];
    const int* wr = (const int*)d_in[1];
    const int* wo = (const int*)d_in[2];
    const int* w4 = (const int*)d_in[3];
    const int* t1 = (const int*)d_in[4];
    const int* t2 = (const int*)d_in[5];
    const int* t3 = (const int*)d_in[6];
    const int* t4 = (const int*)d_in[7];
    const int* q  = (const int*)d_in[8];
    const float* g = (const float*)d_in[9];
    const int* zp = (const int*)d_in[10];

    char* ws = (char*)d_ws;
    uint32_t* Wfull  = (uint32_t*)(ws);                       // 8 MB (2^21 u32, stage-packed Montgomery)
    uint32_t* tcomp  = (uint32_t*)(ws + (8ull  << 20));       // 8 MB
    uint32_t* fcomp  = (uint32_t*)(ws + (16ull << 20));       // 8 MB
    uint32_t* h1     = (uint32_t*)(ws + (24ull << 20));       // 8 MB
    uint32_t* h2     = (uint32_t*)(ws + (32ull << 20));       // 8 MB
    // small buffers: each at its own 64 KiB-aligned offset (dacc must be 8-aligned!)
    unsigned int* hist    = (unsigned int*)(ws + (40ull << 20));                  // 32 KB used
    unsigned int* basearr = (unsigned int*)(ws + (40ull << 20) + (64u  << 10));   // 32 KB+4 used
    unsigned int* cursor  = (unsigned int*)(ws + (40ull << 20) + (128u << 10));   // 32 KB used
    double*       dacc    = (double*)     (ws + (40ull << 20) + (192u << 10));    // 192 B used
    uint32_t*     tA      = (uint32_t*)   (ws + (40ull << 20) + (200u << 10));    // 4 KB used
    uint32_t*     tB      = (uint32_t*)   (ws + (40ull << 20) + (208u << 10));    // 4 KB used

    float* outf = (float*)d_out;
    uint32_t* outpolys = (uint32_t*)outf + 24;        // 8*N int32 scratch -> final floats
    uint32_t* barr = (uint32_t*)outf + 1024;          // 16 MB bucket scratch (used before NTT writes)

    hipMemsetAsync(hist, 0, NBUCK * sizeof(unsigned int), stream);
    hipMemsetAsync(dacc, 0, 24 * sizeof(double), stream);

    twiddle_ab_kernel<<<4, 256, 0, stream>>>(tA, tB);
    twiddle_fill_kernel<<<(NN) / 256, 256, 0, stream>>>(tA, tB, Wfull);

    compress_kernel<<<NN / 256, 256, 0, stream>>>(wl, wr, wo, w4, t1, t2, t3, t4, q, zp, tcomp, fcomp);
    hist_kernel<<<4096, 256, 0, stream>>>(tcomp, fcomp, hist);
    scan_kernel<<<1, 256, 0, stream>>>(hist, basearr, cursor);
    scatter_kernel<<<4096, 256, 0, stream>>>(tcomp, fcomp, cursor, barr);
    bucket_sort_kernel<<<NBUCK, 256, 0, stream>>>(barr, basearr, h1, h2);

    SrcPtrs sp;
    sp.p[0] = (const uint32_t*)wl;
    sp.p[1] = (const uint32_t*)wr;
    sp.p[2] = (const uint32_t*)wo;
    sp.p[3] = (const uint32_t*)w4;
    sp.p[4] = tcomp;
    sp.p[5] = fcomp;
    sp.p[6] = h1;
    sp.p[7] = h2;
    bitrev_kernel<<<dim3(512, 8), 256, 0, stream>>>(sp, outpolys);
    ntt_phase1_kernel<<<dim3(512, 8), 256, 0, stream>>>(outpolys, Wfull);
    ntt_phase2_kernel<<<dim3(256, 8), 256, 0, stream>>>(outpolys, Wfull);

    commit_kernel<<<256, 256, 0, stream>>>(outpolys, g, dacc);
    finalize_commits_kernel<<<1, 64, 0, stream>>>(dacc, outf);
    convert_kernel<<<(8u * NN) / 256, 256, 0, stream>>>((float*)outpolys);
}

// Round 5
// 555.308 us; speedup vs baseline: 2.4885x; 1.4477x over previous
//
#include <hip/hip_runtime.h>
#include <stdint.h>

#define PRIME 2013265921u
#define LOGN 21
#define NN (1u << LOGN)   // 2097152

// ---------- compile-time modular helpers ----------
constexpr uint32_t cpow(uint64_t b, uint64_t e) {
    uint64_t r = 1;
    b %= PRIME;
    while (e) {
        if (e & 1ull) r = r * b % PRIME;
        b = b * b % PRIME;
        e >>= 1;
    }
    return (uint32_t)r;
}
constexpr uint32_t cpinv() {           // PRIME^{-1} mod 2^32 (Newton)
    uint32_t inv = 1;
    for (int i = 0; i < 6; i++) inv *= 2u - PRIME * inv;
    return inv;
}
constexpr uint32_t NPRIME   = (uint32_t)(0u - cpinv());            // -P^{-1} mod 2^32
constexpr uint32_t RMODP    = (uint32_t)((1ull << 32) % PRIME);    // Mont(1)
constexpr uint32_t ROOT     = cpow(31u, (PRIME - 1) / NN);
constexpr uint32_t IROOT    = cpow(ROOT, PRIME - 2);
constexpr uint32_t IROOT1K  = cpow(IROOT, 1024);
constexpr uint32_t NINV     = cpow(NN, PRIME - 2);
constexpr uint32_t NINV_M   = (uint32_t)((((uint64_t)NINV) << 32) % PRIME);  // Mont(N^-1)

// ---------- modular arithmetic ----------
__device__ __forceinline__ uint32_t addmod(uint32_t a, uint32_t b) {
    uint32_t s = a + b; return (s >= PRIME) ? s - PRIME : s;
}
__device__ __forceinline__ uint32_t submod(uint32_t a, uint32_t b) {
    return (a >= b) ? (a - b) : (a + PRIME - b);
}
__device__ __forceinline__ uint32_t mulmod(uint32_t a, uint32_t b) {
    return (uint32_t)(((uint64_t)a * (uint64_t)b) % PRIME);
}
// Montgomery: montmul(a_normal, Mont(b)) = a*b mod P; montmul(Mont(a),Mont(b)) = Mont(ab)
__device__ __forceinline__ uint32_t montmul(uint32_t a, uint32_t b) {
    uint64_t t = (uint64_t)a * b;
    uint32_t m = (uint32_t)t * NPRIME;
    uint32_t u = (uint32_t)((t + (uint64_t)m * PRIME) >> 32);
    return (u >= PRIME) ? u - PRIME : u;
}
__device__ uint32_t powmod(uint32_t b, uint32_t e) {
    uint32_t r = 1u;
    while (e) {
        if (e & 1u) r = mulmod(r, b);
        b = mulmod(b, b);
        e >>= 1;
    }
    return r;
}
__device__ __forceinline__ uint32_t tomont(uint32_t x) {
    return (uint32_t)((((uint64_t)x) << 32) % PRIME);
}

// ---------- twiddles: A[i]=Mont(iroot^(1024 i)), B[i]=Mont(iroot^i), i<1024 ----------
__global__ void twiddle_ab_kernel(uint32_t* __restrict__ A, uint32_t* __restrict__ B) {
    uint32_t i = blockIdx.x * blockDim.x + threadIdx.x;   // < 1024
    B[i] = tomont(powmod(IROOT, i));
    A[i] = tomont(powmod(IROOT1K, i));
}
// Stage-packed table: Wfull[2^s + j] = Mont(iroot^(j << (20 - s))), j < 2^s, s=0..20
__global__ void twiddle_fill_kernel(const uint32_t* __restrict__ A, const uint32_t* __restrict__ B,
                                    uint32_t* __restrict__ Wfull) {
    uint32_t idx = blockIdx.x * blockDim.x + threadIdx.x;   // < 2^21
    if (idx == 0) { Wfull[0] = RMODP; return; }
    uint32_t s = 31u - __clz(idx);
    uint32_t j = idx ^ (1u << s);
    uint32_t e = j << (20u - s);                 // < 2^20
    Wfull[idx] = montmul(A[e >> 10], B[e & 1023u]);
}

// ---------- compress + fused coarse (64-bucket) histogram ----------
__global__ __launch_bounds__(256) void compress_kernel(
        const int* __restrict__ wl, const int* __restrict__ wr,
        const int* __restrict__ wo, const int* __restrict__ w4,
        const int* __restrict__ t1, const int* __restrict__ t2,
        const int* __restrict__ t3, const int* __restrict__ t4,
        const int* __restrict__ q,  const int* __restrict__ zp,
        uint32_t* __restrict__ tcomp, uint32_t* __restrict__ fcomp,
        unsigned int* __restrict__ hist64) {
    __shared__ unsigned int h64[64];
    if (threadIdx.x < 64) h64[threadIdx.x] = 0;
    __syncthreads();
    uint32_t z1 = ((uint32_t)zp[0]) % PRIME;
    uint32_t z2 = mulmod(z1, z1);
    uint32_t z3 = mulmod(z2, z1);
    for (uint32_t i = blockIdx.x * blockDim.x + threadIdx.x; i < NN; i += gridDim.x * blockDim.x) {
        uint32_t t = addmod(addmod((uint32_t)t1[i], mulmod((uint32_t)t2[i], z1)),
                            addmod(mulmod((uint32_t)t3[i], z2), mulmod((uint32_t)t4[i], z3)));
        uint32_t w = addmod(addmod((uint32_t)wl[i], mulmod((uint32_t)wr[i], z1)),
                            addmod(mulmod((uint32_t)wo[i], z2), mulmod((uint32_t)w4[i], z3)));
        uint32_t f = (q[i] != 0) ? w : t;
        tcomp[i] = t;
        fcomp[i] = f;
        atomicAdd(&h64[t >> 25], 1u);
        atomicAdd(&h64[f >> 25], 1u);
    }
    __syncthreads();
    if (threadIdx.x < 64 && h64[threadIdx.x])
        atomicAdd(&hist64[threadIdx.x], h64[threadIdx.x]);
}

// ---------- sort ----------
#define NBUCK 8192

__global__ void scan64_kernel(const unsigned int* __restrict__ hist64,
                              unsigned int* __restrict__ cbase, unsigned int* __restrict__ ccursor) {
    if (threadIdx.x == 0) {
        unsigned int run = 0;
        for (int b = 0; b < 64; b++) { cbase[b] = run; ccursor[b] = run; run += hist64[b]; }
        cbase[64] = run;
    }
}

// pass 1: scatter into 64 coarse buckets with LDS grouping (coalesced run writes)
__global__ __launch_bounds__(256) void pass1_kernel(const uint32_t* __restrict__ tcomp,
                                                    const uint32_t* __restrict__ fcomp,
                                                    unsigned int* __restrict__ ccursor,
                                                    uint32_t* __restrict__ barr1) {
    __shared__ uint32_t grp[4096];
    __shared__ unsigned char grpb[4096];
    __shared__ unsigned int cnt[64], pref[64], curs[64], rbase[64];
    uint32_t base = blockIdx.x * 4096;    // grid 1024 covers 2NN exactly
    uint32_t tid = threadIdx.x;
    if (tid < 64) cnt[tid] = 0;
    __syncthreads();
    for (uint32_t l = tid; l < 4096; l += 256) {
        uint32_t gi = base + l;
        uint32_t v = (gi < NN) ? tcomp[gi] : fcomp[gi - NN];
        atomicAdd(&cnt[v >> 25], 1u);
    }
    __syncthreads();
    if (tid == 0) {
        unsigned int run = 0;
        for (int b = 0; b < 64; b++) { pref[b] = run; curs[b] = run; run += cnt[b]; }
    }
    __syncthreads();
    if (tid < 64 && cnt[tid]) rbase[tid] = atomicAdd(&ccursor[tid], cnt[tid]);
    for (uint32_t l = tid; l < 4096; l += 256) {
        uint32_t gi = base + l;
        uint32_t v = (gi < NN) ? tcomp[gi] : fcomp[gi - NN];
        uint32_t b = v >> 25;
        unsigned int p = atomicAdd(&curs[b], 1u);
        grp[p] = v; grpb[p] = (unsigned char)b;
    }
    __syncthreads();
    for (uint32_t l = tid; l < 4096; l += 256) {
        uint32_t b = grpb[l];
        barr1[rbase[b] + (l - pref[b])] = grp[l];
    }
}

// fine (8192-bucket) histogram from coarse-partitioned data
__global__ __launch_bounds__(256) void fine_hist_kernel(const uint32_t* __restrict__ barr1,
                                                        const unsigned int* __restrict__ cbase,
                                                        unsigned int* __restrict__ hist) {
    __shared__ unsigned int cnt[128];
    uint32_t tid = threadIdx.x;
    uint32_t reg = blockIdx.y;
    if (tid < 128) cnt[tid] = 0;
    __syncthreads();
    uint32_t lo = cbase[reg], hi = cbase[reg + 1];
    for (uint32_t i = lo + blockIdx.x * 256 + tid; i < hi; i += gridDim.x * 256)
        atomicAdd(&cnt[(barr1[i] >> 18) & 127u], 1u);
    __syncthreads();
    if (tid < 128 && cnt[tid]) atomicAdd(&hist[reg * 128 + tid], cnt[tid]);
}

__global__ void scan_kernel(const unsigned int* __restrict__ hist,
                            unsigned int* __restrict__ basearr, unsigned int* __restrict__ fcursor) {
    __shared__ unsigned int ls[256];
    int t = threadIdx.x;
    unsigned int local[32];
    unsigned int s = 0;
    for (int k = 0; k < 32; k++) { local[k] = hist[t * 32 + k]; s += local[k]; }
    ls[t] = s;
    __syncthreads();
    for (int off = 1; off < 256; off <<= 1) {
        unsigned int v = (t >= off) ? ls[t - off] : 0u;
        __syncthreads();
        ls[t] += v;
        __syncthreads();
    }
    unsigned int run = ls[t] - s;  // exclusive prefix
    for (int k = 0; k < 32; k++) {
        basearr[t * 32 + k] = run;
        fcursor[t * 32 + k] = run;
        run += local[k];
    }
    if (t == 255) basearr[NBUCK] = run;
}

// pass 2: within each coarse region, scatter into 128 fine buckets (LDS grouping)
__global__ __launch_bounds__(256) void pass2_kernel(const uint32_t* __restrict__ barr1,
                                                    const unsigned int* __restrict__ cbase,
                                                    unsigned int* __restrict__ fcursor,
                                                    uint32_t* __restrict__ barr2) {
    __shared__ uint32_t grp[4096];
    __shared__ unsigned char grpb[4096];
    __shared__ unsigned int cnt[128], pref[128], curs[128], rbase[128];
    uint32_t tid = threadIdx.x;
    uint32_t reg = blockIdx.y;
    uint32_t lo = cbase[reg], hi = cbase[reg + 1];
    for (uint32_t start = lo + blockIdx.x * 4096; start < hi; start += gridDim.x * 4096) {
        uint32_t n = min(4096u, hi - start);
        if (tid < 128) cnt[tid] = 0;
        __syncthreads();
        for (uint32_t l = tid; l < n; l += 256)
            atomicAdd(&cnt[(barr1[start + l] >> 18) & 127u], 1u);
        __syncthreads();
        if (tid == 0) {
            unsigned int run = 0;
            for (int b = 0; b < 128; b++) { pref[b] = run; curs[b] = run; run += cnt[b]; }
        }
        __syncthreads();
        if (tid < 128 && cnt[tid]) rbase[tid] = atomicAdd(&fcursor[reg * 128 + tid], cnt[tid]);
        for (uint32_t l = tid; l < n; l += 256) {
            uint32_t v = barr1[start + l];
            uint32_t b = (v >> 18) & 127u;
            unsigned int p = atomicAdd(&curs[b], 1u);
            grp[p] = v; grpb[p] = (unsigned char)b;
        }
        __syncthreads();
        for (uint32_t l = tid; l < n; l += 256) {
            uint32_t b = grpb[l];
            barr2[rbase[b] + (l - pref[b])] = grp[l];
        }
        __syncthreads();
    }
}

__global__ void bucket_sort_kernel(const uint32_t* __restrict__ barr, const unsigned int* __restrict__ basearr,
                                   uint32_t* __restrict__ h1, uint32_t* __restrict__ h2) {
    __shared__ uint32_t sd[4096];
    uint32_t b  = blockIdx.x;
    uint32_t lo = basearr[b], hi = basearr[b + 1];
    uint32_t n  = hi - lo;
    if (n == 0) return;
    uint32_t np = 1; while (np < n) np <<= 1;
    if (np > 4096) np = 4096;   // unreachable for this distribution
    for (uint32_t i = threadIdx.x; i < np; i += blockDim.x)
        sd[i] = (i < n) ? barr[lo + i] : 0xFFFFFFFFu;
    __syncthreads();
    for (uint32_t k = 2; k <= np; k <<= 1) {
        for (uint32_t j = k >> 1; j > 0; j >>= 1) {
            for (uint32_t i = threadIdx.x; i < np; i += blockDim.x) {
                uint32_t ixj = i ^ j;
                if (ixj > i) {
                    uint32_t a = sd[i], c = sd[ixj];
                    bool up = ((i & k) == 0);
                    if ((a > c) == up) { sd[i] = c; sd[ixj] = a; }
                }
            }
            __syncthreads();
        }
    }
    for (uint32_t i = threadIdx.x; i < n; i += blockDim.x) {
        uint32_t p = lo + i, v = sd[i];
        if (p & 1) h2[p >> 1] = v; else h1[p >> 1] = v;
    }
}

// ---------- bit-reversal permute: dst[i] = src[rev21(i)], tiled ----------
struct SrcPtrs { const uint32_t* p[8]; };

__global__ void bitrev_kernel(SrcPtrs srcs, uint32_t* __restrict__ dst) {
    __shared__ uint32_t tile[64 * 65];
    uint32_t poly = blockIdx.y;
    const uint32_t* src = srcs.p[poly];
    uint32_t* out = dst + (size_t)poly * NN;
    uint32_t m  = blockIdx.x;                 // 9-bit middle
    uint32_t rm = __brev(m) >> 23;            // rev9
    for (uint32_t l = threadIdx.x; l < 4096; l += blockDim.x) {
        uint32_t u = l >> 6, v = l & 63;
        tile[u * 65 + v] = src[(u << 15) | (rm << 6) | v];
    }
    __syncthreads();
    for (uint32_t l = threadIdx.x; l < 4096; l += blockDim.x) {
        uint32_t a = l >> 6, b = l & 63;
        uint32_t ra = __brev(a) >> 26, rb = __brev(b) >> 26;  // rev6
        out[(a << 15) | (m << 6) | b] = tile[rb * 65 + ra];
    }
}

// ---------- NTT stages 1..12 in LDS; twiddles preloaded to LDS; n_inv folded in ----------
__device__ __forceinline__ uint32_t padi(uint32_t i) { return i + (i >> 5); }

__global__ __launch_bounds__(256) void ntt_phase1_kernel(uint32_t* __restrict__ polys,
                                                         const uint32_t* __restrict__ Wfull) {
    __shared__ uint32_t wt[4096];
    __shared__ uint32_t sd[4224];     // padded: i + (i>>5)
    uint32_t* x = polys + (size_t)blockIdx.y * NN + (size_t)blockIdx.x * 4096;
    for (uint32_t l = threadIdx.x; l < 4096; l += 256) {
        wt[l] = Wfull[l];
        sd[padi(l)] = x[l];
    }
    __syncthreads();
    for (int st = 1; st <= 12; st++) {
        uint32_t half = 1u << (st - 1);
        #pragma unroll 2
        for (uint32_t bf = threadIdx.x; bf < 2048; bf += 256) {
            uint32_t j  = bf & (half - 1);
            uint32_t g  = bf >> (st - 1);
            uint32_t i0 = (g << st) + j, i1 = i0 + half;
            uint32_t w = wt[half + j];
            uint32_t u = sd[padi(i0)];
            uint32_t v = montmul(sd[padi(i1)], w);
            sd[padi(i0)] = addmod(u, v);
            sd[padi(i1)] = submod(u, v);
        }
        __syncthreads();
    }
    // fold in N^-1 scaling here (linear, commutes with remaining stages)
    for (uint32_t l = threadIdx.x; l < 4096; l += 256)
        x[l] = montmul(sd[padi(l)], NINV_M);
}

// ---------- NTT stages 13..21: 16 cols x 512 rows tile; factored twiddles; float output ----------
__device__ __forceinline__ uint32_t pad16(uint32_t idx) { return idx + (idx >> 5); }

__global__ __launch_bounds__(256) void ntt_phase2_kernel(uint32_t* __restrict__ polys,
                                                         const uint32_t* __restrict__ Wfull) {
    __shared__ uint32_t sd[8448];     // 8192 data + pad
    __shared__ uint32_t rowt[512];    // rowt[hb+kk] = Mont(iroot^(kk·4096 << (8-s)))
    uint32_t* x = polys + (size_t)blockIdx.y * NN;
    uint32_t c0 = blockIdx.x * 16;
    uint32_t tid = threadIdx.x;
    uint32_t c = tid & 15u;
    uint32_t rt = tid >> 4;           // 0..15

    for (uint32_t l = tid; l < 8192; l += 256) {
        uint32_t b = l >> 4, cc = l & 15;
        sd[pad16(l)] = x[c0 + cc + (b << 12)];
    }
    rowt[tid]       = (tid == 0) ? RMODP : Wfull[tid << 12];
    rowt[tid + 256] = Wfull[(uint32_t)(tid + 256) << 12];
    uint32_t cw[9];
    #pragma unroll
    for (int s = 0; s < 9; s++) cw[s] = Wfull[(1u << (12 + s)) + c0 + c];
    __syncthreads();

    #pragma unroll
    for (int s = 0; s < 9; s++) {     // stage st = 13 + s
        uint32_t hb = 1u << s;
        #pragma unroll 4
        for (uint32_t m = 0; m < 16; m++) {
            uint32_t p  = (rt << 4) + m;          // pair index 0..255
            uint32_t kk = p & (hb - 1);
            uint32_t g  = p >> s;
            uint32_t b0 = (g << (s + 1)) + kk, b1 = b0 + hb;
            uint32_t w = montmul(rowt[hb + kk], cw[s]);
            uint32_t i0 = pad16((b0 << 4) + c), i1 = pad16((b1 << 4) + c);
            uint32_t u = sd[i0];
            uint32_t v = montmul(sd[i1], w);
            sd[i0] = addmod(u, v);
            sd[i1] = submod(u, v);
        }
        __syncthreads();
    }

    // epilogue: write FINAL float values (convert fused here)
    float* xf = (float*)x;
    for (uint32_t l = tid; l < 8192; l += 256) {
        uint32_t b = l >> 4, cc = l & 15;
        xf[c0 + cc + (b << 12)] = (float)sd[pad16(l)];
    }
}

// ---------- commits: read float polys + g once, accumulate in f64 ----------
__global__ void commit_kernel(const float* __restrict__ polys, const float* __restrict__ g,
                              double* __restrict__ dacc) {
    double acc[24];
    #pragma unroll
    for (int k = 0; k < 24; k++) acc[k] = 0.0;
    const float invp = (float)(1.0 / 2013265921.0);
    for (uint32_t i = blockIdx.x * blockDim.x + threadIdx.x; i < NN; i += gridDim.x * blockDim.x) {
        float g0 = g[i * 3 + 0], g1 = g[i * 3 + 1], g2 = g[i * 3 + 2];
        #pragma unroll
        for (int p = 0; p < 8; p++) {
            float s = polys[(size_t)p * NN + i] * invp;
            acc[p * 3 + 0] += (double)(s * g0);
            acc[p * 3 + 1] += (double)(s * g1);
            acc[p * 3 + 2] += (double)(s * g2);
        }
    }
    __shared__ double red[256];
    for (int k = 0; k < 24; k++) {
        red[threadIdx.x] = acc[k];
        __syncthreads();
        for (int off = 128; off > 0; off >>= 1) {
            if (threadIdx.x < off) red[threadIdx.x] += red[threadIdx.x + off];
            __syncthreads();
        }
        if (threadIdx.x == 0) atomicAdd(&dacc[k], red[0]);
        __syncthreads();
    }
}

__global__ void finalize_commits_kernel(const double* __restrict__ dacc, float* __restrict__ outf) {
    int t = threadIdx.x;
    if (t < 24) outf[t] = (float)dacc[t];
}

extern "C" void kernel_launch(void* const* d_in, const int* in_sizes, int n_in,
                              void* d_out, int out_size, void* d_ws, size_t ws_size,
                              hipStream_t stream) {
    const int* wl = (const int*)d_in[0];
    const int* wr = (const int*)d_in[1];
    const int* wo = (const int*)d_in[2];
    const int* w4 = (const int*)d_in[3];
    const int* t1 = (const int*)d_in[4];
    const int* t2 = (const int*)d_in[5];
    const int* t3 = (const int*)d_in[6];
    const int* t4 = (const int*)d_in[7];
    const int* q  = (const int*)d_in[8];
    const float* g = (const float*)d_in[9];
    const int* zp = (const int*)d_in[10];

    char* ws = (char*)d_ws;
    uint32_t* Wfull  = (uint32_t*)(ws);                       // 8 MB
    uint32_t* tcomp  = (uint32_t*)(ws + (8ull  << 20));       // 8 MB
    uint32_t* fcomp  = (uint32_t*)(ws + (16ull << 20));       // 8 MB
    uint32_t* h1     = (uint32_t*)(ws + (24ull << 20));       // 8 MB
    uint32_t* h2     = (uint32_t*)(ws + (32ull << 20));       // 8 MB
    // small buffers at 64 KiB-aligned offsets (dacc 8-aligned)
    unsigned int* hist    = (unsigned int*)(ws + (40ull << 20));                  // 32 KB
    unsigned int* basearr = (unsigned int*)(ws + (40ull << 20) + (64u  << 10));   // 32 KB+4
    unsigned int* fcursor = (unsigned int*)(ws + (40ull << 20) + (128u << 10));   // 32 KB
    double*       dacc    = (double*)     (ws + (40ull << 20) + (192u << 10));    // 192 B
    uint32_t*     tA      = (uint32_t*)   (ws + (40ull << 20) + (200u << 10));    // 4 KB
    uint32_t*     tB      = (uint32_t*)   (ws + (40ull << 20) + (208u << 10));    // 4 KB
    unsigned int* hist64  = (unsigned int*)(ws + (40ull << 20) + (216u << 10));   // 256 B
    unsigned int* cbase   = (unsigned int*)(ws + (40ull << 20) + (224u << 10));   // 260 B
    unsigned int* ccursor = (unsigned int*)(ws + (40ull << 20) + (232u << 10));   // 256 B

    float* outf = (float*)d_out;
    uint32_t* outpolys = (uint32_t*)outf + 24;                      // 8*N, final floats
    uint32_t* barr1 = (uint32_t*)outf + 1024;                       // 16 MB scratch (pre-NTT)
    uint32_t* barr2 = (uint32_t*)outf + 1024 + (5u << 20);          // 16 MB scratch (pre-NTT)

    hipMemsetAsync(hist, 0, NBUCK * sizeof(unsigned int), stream);
    hipMemsetAsync(hist64, 0, 64 * sizeof(unsigned int), stream);
    hipMemsetAsync(dacc, 0, 24 * sizeof(double), stream);

    twiddle_ab_kernel<<<4, 256, 0, stream>>>(tA, tB);
    twiddle_fill_kernel<<<NN / 256, 256, 0, stream>>>(tA, tB, Wfull);

    compress_kernel<<<2048, 256, 0, stream>>>(wl, wr, wo, w4, t1, t2, t3, t4, q, zp,
                                              tcomp, fcomp, hist64);
    scan64_kernel<<<1, 64, 0, stream>>>(hist64, cbase, ccursor);
    pass1_kernel<<<1024, 256, 0, stream>>>(tcomp, fcomp, ccursor, barr1);
    fine_hist_kernel<<<dim3(16, 64), 256, 0, stream>>>(barr1, cbase, hist);
    scan_kernel<<<1, 256, 0, stream>>>(hist, basearr, fcursor);
    pass2_kernel<<<dim3(16, 64), 256, 0, stream>>>(barr1, cbase, fcursor, barr2);
    bucket_sort_kernel<<<NBUCK, 256, 0, stream>>>(barr2, basearr, h1, h2);

    SrcPtrs sp;
    sp.p[0] = (const uint32_t*)wl;
    sp.p[1] = (const uint32_t*)wr;
    sp.p[2] = (const uint32_t*)wo;
    sp.p[3] = (const uint32_t*)w4;
    sp.p[4] = tcomp;
    sp.p[5] = fcomp;
    sp.p[6] = h1;
    sp.p[7] = h2;
    bitrev_kernel<<<dim3(512, 8), 256, 0, stream>>>(sp, outpolys);
    ntt_phase1_kernel<<<dim3(512, 8), 256, 0, stream>>>(outpolys, Wfull);
    ntt_phase2_kernel<<<dim3(256, 8), 256, 0, stream>>>(outpolys, Wfull);

    commit_kernel<<<256, 256, 0, stream>>>((const float*)outpolys, g, dacc);
    finalize_commits_kernel<<<1, 64, 0, stream>>>(dacc, outf);
}

// Round 6
// 546.022 us; speedup vs baseline: 2.5308x; 1.0170x over previous
//
#include <hip/hip_runtime.h>
#include <stdint.h>

#define PRIME 2013265921u
#define LOGN 21
#define NN (1u << LOGN)   // 2097152

// ---------- compile-time modular helpers ----------
constexpr uint32_t cpow(uint64_t b, uint64_t e) {
    uint64_t r = 1;
    b %= PRIME;
    while (e) {
        if (e & 1ull) r = r * b % PRIME;
        b = b * b % PRIME;
        e >>= 1;
    }
    return (uint32_t)r;
}
constexpr uint32_t cpinv() {           // PRIME^{-1} mod 2^32 (Newton)
    uint32_t inv = 1;
    for (int i = 0; i < 6; i++) inv *= 2u - PRIME * inv;
    return inv;
}
constexpr uint32_t NPRIME   = (uint32_t)(0u - cpinv());            // -P^{-1} mod 2^32
constexpr uint32_t RMODP    = (uint32_t)((1ull << 32) % PRIME);    // Mont(1)
constexpr uint32_t ROOT     = cpow(31u, (PRIME - 1) / NN);
constexpr uint32_t IROOT    = cpow(ROOT, PRIME - 2);
constexpr uint32_t IROOT1K  = cpow(IROOT, 1024);
constexpr uint32_t NINV     = cpow(NN, PRIME - 2);
constexpr uint32_t NINV_M   = (uint32_t)((((uint64_t)NINV) << 32) % PRIME);  // Mont(N^-1)

// ---------- modular arithmetic ----------
__device__ __forceinline__ uint32_t addmod(uint32_t a, uint32_t b) {
    uint32_t s = a + b; return (s >= PRIME) ? s - PRIME : s;
}
__device__ __forceinline__ uint32_t submod(uint32_t a, uint32_t b) {
    return (a >= b) ? (a - b) : (a + PRIME - b);
}
__device__ __forceinline__ uint32_t mulmod(uint32_t a, uint32_t b) {
    return (uint32_t)(((uint64_t)a * (uint64_t)b) % PRIME);
}
// Montgomery: montmul(a_normal, Mont(b)) = a*b mod P; montmul(Mont(a),Mont(b)) = Mont(ab)
__device__ __forceinline__ uint32_t montmul(uint32_t a, uint32_t b) {
    uint64_t t = (uint64_t)a * b;
    uint32_t m = (uint32_t)t * NPRIME;
    uint32_t u = (uint32_t)((t + (uint64_t)m * PRIME) >> 32);
    return (u >= PRIME) ? u - PRIME : u;
}
__device__ uint32_t powmod(uint32_t b, uint32_t e) {
    uint32_t r = 1u;
    while (e) {
        if (e & 1u) r = mulmod(r, b);
        b = mulmod(b, b);
        e >>= 1;
    }
    return r;
}
__device__ __forceinline__ uint32_t tomont(uint32_t x) {
    return (uint32_t)((((uint64_t)x) << 32) % PRIME);
}

// ---------- twiddles: A[i]=Mont(iroot^(1024 i)), B[i]=Mont(iroot^i), i<1024 ----------
__global__ void twiddle_ab_kernel(uint32_t* __restrict__ A, uint32_t* __restrict__ B) {
    uint32_t i = blockIdx.x * blockDim.x + threadIdx.x;   // < 1024
    B[i] = tomont(powmod(IROOT, i));
    A[i] = tomont(powmod(IROOT1K, i));
}
// Stage-packed table: Wfull[2^s + j] = Mont(iroot^(j << (20 - s))), j < 2^s, s=0..20
__global__ void twiddle_fill_kernel(const uint32_t* __restrict__ A, const uint32_t* __restrict__ B,
                                    uint32_t* __restrict__ Wfull) {
    uint32_t idx = blockIdx.x * blockDim.x + threadIdx.x;   // < 2^21
    if (idx == 0) { Wfull[0] = RMODP; return; }
    uint32_t s = 31u - __clz(idx);
    uint32_t j = idx ^ (1u << s);
    uint32_t e = j << (20u - s);                 // < 2^20
    Wfull[idx] = montmul(A[e >> 10], B[e & 1023u]);
}

// ---------- compress + fused coarse (64-bucket) histogram ----------
__global__ __launch_bounds__(256) void compress_kernel(
        const int* __restrict__ wl, const int* __restrict__ wr,
        const int* __restrict__ wo, const int* __restrict__ w4,
        const int* __restrict__ t1, const int* __restrict__ t2,
        const int* __restrict__ t3, const int* __restrict__ t4,
        const int* __restrict__ q,  const int* __restrict__ zp,
        uint32_t* __restrict__ tcomp, uint32_t* __restrict__ fcomp,
        unsigned int* __restrict__ hist64) {
    __shared__ unsigned int h64[64];
    if (threadIdx.x < 64) h64[threadIdx.x] = 0;
    __syncthreads();
    uint32_t z1 = ((uint32_t)zp[0]) % PRIME;
    uint32_t z2 = mulmod(z1, z1);
    uint32_t z3 = mulmod(z2, z1);
    for (uint32_t i = blockIdx.x * blockDim.x + threadIdx.x; i < NN; i += gridDim.x * blockDim.x) {
        uint32_t t = addmod(addmod((uint32_t)t1[i], mulmod((uint32_t)t2[i], z1)),
                            addmod(mulmod((uint32_t)t3[i], z2), mulmod((uint32_t)t4[i], z3)));
        uint32_t w = addmod(addmod((uint32_t)wl[i], mulmod((uint32_t)wr[i], z1)),
                            addmod(mulmod((uint32_t)wo[i], z2), mulmod((uint32_t)w4[i], z3)));
        uint32_t f = (q[i] != 0) ? w : t;
        tcomp[i] = t;
        fcomp[i] = f;
        atomicAdd(&h64[t >> 25], 1u);
        atomicAdd(&h64[f >> 25], 1u);
    }
    __syncthreads();
    if (threadIdx.x < 64 && h64[threadIdx.x])
        atomicAdd(&hist64[threadIdx.x], h64[threadIdx.x]);
}

// ---------- sort ----------
#define NBUCK 8192

__global__ void scan64_kernel(const unsigned int* __restrict__ hist64,
                              unsigned int* __restrict__ cbase, unsigned int* __restrict__ ccursor) {
    if (threadIdx.x == 0) {
        unsigned int run = 0;
        for (int b = 0; b < 64; b++) { cbase[b] = run; ccursor[b] = run; run += hist64[b]; }
        cbase[64] = run;
    }
}

// pass 1: scatter into 64 coarse buckets with LDS grouping (coalesced run writes)
__global__ __launch_bounds__(256) void pass1_kernel(const uint32_t* __restrict__ tcomp,
                                                    const uint32_t* __restrict__ fcomp,
                                                    unsigned int* __restrict__ ccursor,
                                                    uint32_t* __restrict__ barr1) {
    __shared__ uint32_t grp[4096];
    __shared__ unsigned char grpb[4096];
    __shared__ unsigned int cnt[64], pref[64], curs[64], rbase[64];
    uint32_t base = blockIdx.x * 4096;    // grid 1024 covers 2NN exactly
    uint32_t tid = threadIdx.x;
    if (tid < 64) cnt[tid] = 0;
    __syncthreads();
    for (uint32_t l = tid; l < 4096; l += 256) {
        uint32_t gi = base + l;
        uint32_t v = (gi < NN) ? tcomp[gi] : fcomp[gi - NN];
        atomicAdd(&cnt[v >> 25], 1u);
    }
    __syncthreads();
    if (tid == 0) {
        unsigned int run = 0;
        for (int b = 0; b < 64; b++) { pref[b] = run; curs[b] = run; run += cnt[b]; }
    }
    __syncthreads();
    if (tid < 64 && cnt[tid]) rbase[tid] = atomicAdd(&ccursor[tid], cnt[tid]);
    for (uint32_t l = tid; l < 4096; l += 256) {
        uint32_t gi = base + l;
        uint32_t v = (gi < NN) ? tcomp[gi] : fcomp[gi - NN];
        uint32_t b = v >> 25;
        unsigned int p = atomicAdd(&curs[b], 1u);
        grp[p] = v; grpb[p] = (unsigned char)b;
    }
    __syncthreads();
    for (uint32_t l = tid; l < 4096; l += 256) {
        uint32_t b = grpb[l];
        barr1[rbase[b] + (l - pref[b])] = grp[l];
    }
}

// fine (8192-bucket) histogram from coarse-partitioned data
__global__ __launch_bounds__(256) void fine_hist_kernel(const uint32_t* __restrict__ barr1,
                                                        const unsigned int* __restrict__ cbase,
                                                        unsigned int* __restrict__ hist) {
    __shared__ unsigned int cnt[128];
    uint32_t tid = threadIdx.x;
    uint32_t reg = blockIdx.y;
    if (tid < 128) cnt[tid] = 0;
    __syncthreads();
    uint32_t lo = cbase[reg], hi = cbase[reg + 1];
    for (uint32_t i = lo + blockIdx.x * 256 + tid; i < hi; i += gridDim.x * 256)
        atomicAdd(&cnt[(barr1[i] >> 18) & 127u], 1u);
    __syncthreads();
    if (tid < 128 && cnt[tid]) atomicAdd(&hist[reg * 128 + tid], cnt[tid]);
}

__global__ void scan_kernel(const unsigned int* __restrict__ hist,
                            unsigned int* __restrict__ basearr, unsigned int* __restrict__ fcursor) {
    __shared__ unsigned int ls[256];
    int t = threadIdx.x;
    unsigned int local[32];
    unsigned int s = 0;
    for (int k = 0; k < 32; k++) { local[k] = hist[t * 32 + k]; s += local[k]; }
    ls[t] = s;
    __syncthreads();
    for (int off = 1; off < 256; off <<= 1) {
        unsigned int v = (t >= off) ? ls[t - off] : 0u;
        __syncthreads();
        ls[t] += v;
        __syncthreads();
    }
    unsigned int run = ls[t] - s;  // exclusive prefix
    for (int k = 0; k < 32; k++) {
        basearr[t * 32 + k] = run;
        fcursor[t * 32 + k] = run;
        run += local[k];
    }
    if (t == 255) basearr[NBUCK] = run;
}

// pass 2: within each coarse region, scatter into 128 fine buckets (LDS grouping)
__global__ __launch_bounds__(256) void pass2_kernel(const uint32_t* __restrict__ barr1,
                                                    const unsigned int* __restrict__ cbase,
                                                    unsigned int* __restrict__ fcursor,
                                                    uint32_t* __restrict__ barr2) {
    __shared__ uint32_t grp[4096];
    __shared__ unsigned char grpb[4096];
    __shared__ unsigned int cnt[128], pref[128], curs[128], rbase[128];
    uint32_t tid = threadIdx.x;
    uint32_t reg = blockIdx.y;
    uint32_t lo = cbase[reg], hi = cbase[reg + 1];
    for (uint32_t start = lo + blockIdx.x * 4096; start < hi; start += gridDim.x * 4096) {
        uint32_t n = min(4096u, hi - start);
        if (tid < 128) cnt[tid] = 0;
        __syncthreads();
        for (uint32_t l = tid; l < n; l += 256)
            atomicAdd(&cnt[(barr1[start + l] >> 18) & 127u], 1u);
        __syncthreads();
        if (tid == 0) {
            unsigned int run = 0;
            for (int b = 0; b < 128; b++) { pref[b] = run; curs[b] = run; run += cnt[b]; }
        }
        __syncthreads();
        if (tid < 128 && cnt[tid]) rbase[tid] = atomicAdd(&fcursor[reg * 128 + tid], cnt[tid]);
        for (uint32_t l = tid; l < n; l += 256) {
            uint32_t v = barr1[start + l];
            uint32_t b = (v >> 18) & 127u;
            unsigned int p = atomicAdd(&curs[b], 1u);
            grp[p] = v; grpb[p] = (unsigned char)b;
        }
        __syncthreads();
        for (uint32_t l = tid; l < n; l += 256) {
            uint32_t b = grpb[l];
            barr2[rbase[b] + (l - pref[b])] = grp[l];
        }
        __syncthreads();
    }
}

// ---------- per-bucket O(n) MSD counting sort (replaces bitonic) ----------
// Bucket values share top 13 bits; sub-digit = bits 17:11 (128 bins, avg ~4/bin).
// Final rank within sub-bin via direct comparison (strict total order incl. position).
__global__ __launch_bounds__(256) void bucket_sort_kernel(const uint32_t* __restrict__ barr,
                                                          const unsigned int* __restrict__ basearr,
                                                          uint32_t* __restrict__ h1, uint32_t* __restrict__ h2) {
    __shared__ uint32_t ord[4096];
    __shared__ unsigned int cnt[128], pref[128], curs[128];
    uint32_t b  = blockIdx.x;
    uint32_t lo = basearr[b], hi = basearr[b + 1];
    uint32_t n  = hi - lo;
    if (n == 0) return;
    if (n > 4096) n = 4096;   // unreachable for this distribution
    uint32_t tid = threadIdx.x;
    if (tid < 128) cnt[tid] = 0;
    __syncthreads();
    for (uint32_t i = tid; i < n; i += 256)
        atomicAdd(&cnt[(barr[lo + i] >> 11) & 127u], 1u);
    __syncthreads();
    if (tid == 0) {
        unsigned int run = 0;
        for (int d = 0; d < 128; d++) { pref[d] = run; curs[d] = run; run += cnt[d]; }
    }
    __syncthreads();
    for (uint32_t i = tid; i < n; i += 256) {
        uint32_t v = barr[lo + i];
        uint32_t d = (v >> 11) & 127u;
        unsigned int p = atomicAdd(&curs[d], 1u);
        ord[p] = v;
    }
    __syncthreads();
    for (uint32_t p = tid; p < n; p += 256) {
        uint32_t v = ord[p];
        uint32_t d = (v >> 11) & 127u;
        uint32_t l0 = pref[d], l1 = l0 + cnt[d];
        uint32_t r = 0;
        for (uint32_t q = l0; q < l1; q++) {
            uint32_t u = ord[q];
            r += (u < v) || (u == v && q < p);
        }
        uint32_t gp = lo + l0 + r;
        if (gp & 1) h2[gp >> 1] = v; else h1[gp >> 1] = v;
    }
}

// ---------- bit-reversal permute: dst[i] = src[rev21(i)], tiled ----------
struct SrcPtrs { const uint32_t* p[8]; };

__global__ void bitrev_kernel(SrcPtrs srcs, uint32_t* __restrict__ dst) {
    __shared__ uint32_t tile[64 * 65];
    uint32_t poly = blockIdx.y;
    const uint32_t* src = srcs.p[poly];
    uint32_t* out = dst + (size_t)poly * NN;
    uint32_t m  = blockIdx.x;                 // 9-bit middle
    uint32_t rm = __brev(m) >> 23;            // rev9
    for (uint32_t l = threadIdx.x; l < 4096; l += blockDim.x) {
        uint32_t u = l >> 6, v = l & 63;
        tile[u * 65 + v] = src[(u << 15) | (rm << 6) | v];
    }
    __syncthreads();
    for (uint32_t l = threadIdx.x; l < 4096; l += blockDim.x) {
        uint32_t a = l >> 6, b = l & 63;
        uint32_t ra = __brev(a) >> 26, rb = __brev(b) >> 26;  // rev6
        out[(a << 15) | (m << 6) | b] = tile[rb * 65 + ra];
    }
}

// ---------- NTT stages 1..12 in LDS; twiddles preloaded to LDS; n_inv folded in ----------
__device__ __forceinline__ uint32_t padi(uint32_t i) { return i + (i >> 5); }

__global__ __launch_bounds__(256) void ntt_phase1_kernel(uint32_t* __restrict__ polys,
                                                         const uint32_t* __restrict__ Wfull) {
    __shared__ uint32_t wt[4096];
    __shared__ uint32_t sd[4224];     // padded: i + (i>>5)
    uint32_t* x = polys + (size_t)blockIdx.y * NN + (size_t)blockIdx.x * 4096;
    for (uint32_t l = threadIdx.x; l < 4096; l += 256) {
        wt[l] = Wfull[l];
        sd[padi(l)] = x[l];
    }
    __syncthreads();
    for (int st = 1; st <= 12; st++) {
        uint32_t half = 1u << (st - 1);
        #pragma unroll 2
        for (uint32_t bf = threadIdx.x; bf < 2048; bf += 256) {
            uint32_t j  = bf & (half - 1);
            uint32_t g  = bf >> (st - 1);
            uint32_t i0 = (g << st) + j, i1 = i0 + half;
            uint32_t w = wt[half + j];
            uint32_t u = sd[padi(i0)];
            uint32_t v = montmul(sd[padi(i1)], w);
            sd[padi(i0)] = addmod(u, v);
            sd[padi(i1)] = submod(u, v);
        }
        __syncthreads();
    }
    // fold in N^-1 scaling here (linear, commutes with remaining stages)
    for (uint32_t l = threadIdx.x; l < 4096; l += 256)
        x[l] = montmul(sd[padi(l)], NINV_M);
}

// ---------- NTT stages 13..21: 16 cols x 512 rows tile; factored twiddles; float output ----------
__device__ __forceinline__ uint32_t pad16(uint32_t idx) { return idx + (idx >> 5); }

__global__ __launch_bounds__(256) void ntt_phase2_kernel(uint32_t* __restrict__ polys,
                                                         const uint32_t* __restrict__ Wfull) {
    __shared__ uint32_t sd[8448];     // 8192 data + pad
    __shared__ uint32_t rowt[512];    // rowt[hb+kk] = Mont(iroot^(kk·4096 << (8-s)))
    uint32_t* x = polys + (size_t)blockIdx.y * NN;
    uint32_t c0 = blockIdx.x * 16;
    uint32_t tid = threadIdx.x;
    uint32_t c = tid & 15u;
    uint32_t rt = tid >> 4;           // 0..15

    for (uint32_t l = tid; l < 8192; l += 256) {
        uint32_t b = l >> 4, cc = l & 15;
        sd[pad16(l)] = x[c0 + cc + (b << 12)];
    }
    rowt[tid]       = (tid == 0) ? RMODP : Wfull[tid << 12];
    rowt[tid + 256] = Wfull[(uint32_t)(tid + 256) << 12];
    uint32_t cw[9];
    #pragma unroll
    for (int s = 0; s < 9; s++) cw[s] = Wfull[(1u << (12 + s)) + c0 + c];
    __syncthreads();

    #pragma unroll
    for (int s = 0; s < 9; s++) {     // stage st = 13 + s
        uint32_t hb = 1u << s;
        #pragma unroll 4
        for (uint32_t m = 0; m < 16; m++) {
            uint32_t p  = (rt << 4) + m;          // pair index 0..255
            uint32_t kk = p & (hb - 1);
            uint32_t g  = p >> s;
            uint32_t b0 = (g << (s + 1)) + kk, b1 = b0 + hb;
            uint32_t w = montmul(rowt[hb + kk], cw[s]);
            uint32_t i0 = pad16((b0 << 4) + c), i1 = pad16((b1 << 4) + c);
            uint32_t u = sd[i0];
            uint32_t v = montmul(sd[i1], w);
            sd[i0] = addmod(u, v);
            sd[i1] = submod(u, v);
        }
        __syncthreads();
    }

    // epilogue: write FINAL float values (convert fused here)
    float* xf = (float*)x;
    for (uint32_t l = tid; l < 8192; l += 256) {
        uint32_t b = l >> 4, cc = l & 15;
        xf[c0 + cc + (b << 12)] = (float)sd[pad16(l)];
    }
}

// ---------- commits: read float polys + g once, accumulate in f64 ----------
__global__ void commit_kernel(const float* __restrict__ polys, const float* __restrict__ g,
                              double* __restrict__ dacc) {
    double acc[24];
    #pragma unroll
    for (int k = 0; k < 24; k++) acc[k] = 0.0;
    const float invp = (float)(1.0 / 2013265921.0);
    for (uint32_t i = blockIdx.x * blockDim.x + threadIdx.x; i < NN; i += gridDim.x * blockDim.x) {
        float g0 = g[i * 3 + 0], g1 = g[i * 3 + 1], g2 = g[i * 3 + 2];
        #pragma unroll
        for (int p = 0; p < 8; p++) {
            float s = polys[(size_t)p * NN + i] * invp;
            acc[p * 3 + 0] += (double)(s * g0);
            acc[p * 3 + 1] += (double)(s * g1);
            acc[p * 3 + 2] += (double)(s * g2);
        }
    }
    __shared__ double red[256];
    for (int k = 0; k < 24; k++) {
        red[threadIdx.x] = acc[k];
        __syncthreads();
        for (int off = 128; off > 0; off >>= 1) {
            if (threadIdx.x < off) red[threadIdx.x] += red[threadIdx.x + off];
            __syncthreads();
        }
        if (threadIdx.x == 0) atomicAdd(&dacc[k], red[0]);
        __syncthreads();
    }
}

__global__ void finalize_commits_kernel(const double* __restrict__ dacc, float* __restrict__ outf) {
    int t = threadIdx.x;
    if (t < 24) outf[t] = (float)dacc[t];
}

extern "C" void kernel_launch(void* const* d_in, const int* in_sizes, int n_in,
                              void* d_out, int out_size, void* d_ws, size_t ws_size,
                              hipStream_t stream) {
    const int* wl = (const int*)d_in[0];
    const int* wr = (const int*)d_in[1];
    const int* wo = (const int*)d_in[2];
    const int* w4 = (const int*)d_in[3];
    const int* t1 = (const int*)d_in[4];
    const int* t2 = (const int*)d_in[5];
    const int* t3 = (const int*)d_in[6];
    const int* t4 = (const int*)d_in[7];
    const int* q  = (const int*)d_in[8];
    const float* g = (const float*)d_in[9];
    const int* zp = (const int*)d_in[10];

    char* ws = (char*)d_ws;
    uint32_t* Wfull  = (uint32_t*)(ws);                       // 8 MB
    uint32_t* tcomp  = (uint32_t*)(ws + (8ull  << 20));       // 8 MB
    uint32_t* fcomp  = (uint32_t*)(ws + (16ull << 20));       // 8 MB
    uint32_t* h1     = (uint32_t*)(ws + (24ull << 20));       // 8 MB
    uint32_t* h2     = (uint32_t*)(ws + (32ull << 20));       // 8 MB
    // small buffers at 64 KiB-aligned offsets (dacc 8-aligned)
    unsigned int* hist    = (unsigned int*)(ws + (40ull << 20));                  // 32 KB
    unsigned int* basearr = (unsigned int*)(ws + (40ull << 20) + (64u  << 10));   // 32 KB+4
    unsigned int* fcursor = (unsigned int*)(ws + (40ull << 20) + (128u << 10));   // 32 KB
    double*       dacc    = (double*)     (ws + (40ull << 20) + (192u << 10));    // 192 B
    uint32_t*     tA      = (uint32_t*)   (ws + (40ull << 20) + (200u << 10));    // 4 KB
    uint32_t*     tB      = (uint32_t*)   (ws + (40ull << 20) + (208u << 10));    // 4 KB
    unsigned int* hist64  = (unsigned int*)(ws + (40ull << 20) + (216u << 10));   // 256 B
    unsigned int* cbase   = (unsigned int*)(ws + (40ull << 20) + (224u << 10));   // 260 B
    unsigned int* ccursor = (unsigned int*)(ws + (40ull << 20) + (232u << 10));   // 256 B

    float* outf = (float*)d_out;
    uint32_t* outpolys = (uint32_t*)outf + 24;                      // 8*N, final floats
    uint32_t* barr1 = (uint32_t*)outf + 1024;                       // 16 MB scratch (pre-NTT)
    uint32_t* barr2 = (uint32_t*)outf + 1024 + (5u << 20);          // 16 MB scratch (pre-NTT)

    hipMemsetAsync(hist, 0, NBUCK * sizeof(unsigned int), stream);
    hipMemsetAsync(hist64, 0, 64 * sizeof(unsigned int), stream);
    hipMemsetAsync(dacc, 0, 24 * sizeof(double), stream);

    twiddle_ab_kernel<<<4, 256, 0, stream>>>(tA, tB);
    twiddle_fill_kernel<<<NN / 256, 256, 0, stream>>>(tA, tB, Wfull);

    compress_kernel<<<2048, 256, 0, stream>>>(wl, wr, wo, w4, t1, t2, t3, t4, q, zp,
                                              tcomp, fcomp, hist64);
    scan64_kernel<<<1, 64, 0, stream>>>(hist64, cbase, ccursor);
    pass1_kernel<<<1024, 256, 0, stream>>>(tcomp, fcomp, ccursor, barr1);
    fine_hist_kernel<<<dim3(16, 64), 256, 0, stream>>>(barr1, cbase, hist);
    scan_kernel<<<1, 256, 0, stream>>>(hist, basearr, fcursor);
    pass2_kernel<<<dim3(16, 64), 256, 0, stream>>>(barr1, cbase, fcursor, barr2);
    bucket_sort_kernel<<<NBUCK, 256, 0, stream>>>(barr2, basearr, h1, h2);

    SrcPtrs sp;
    sp.p[0] = (const uint32_t*)wl;
    sp.p[1] = (const uint32_t*)wr;
    sp.p[2] = (const uint32_t*)wo;
    sp.p[3] = (const uint32_t*)w4;
    sp.p[4] = tcomp;
    sp.p[5] = fcomp;
    sp.p[6] = h1;
    sp.p[7] = h2;
    bitrev_kernel<<<dim3(512, 8), 256, 0, stream>>>(sp, outpolys);
    ntt_phase1_kernel<<<dim3(512, 8), 256, 0, stream>>>(outpolys, Wfull);
    ntt_phase2_kernel<<<dim3(256, 8), 256, 0, stream>>>(outpolys, Wfull);

    commit_kernel<<<1024, 256, 0, stream>>>((const float*)outpolys, g, dacc);
    finalize_commits_kernel<<<1, 64, 0, stream>>>(dacc, outf);
}

// Round 7
// 387.483 us; speedup vs baseline: 3.5663x; 1.4092x over previous
//
#include <hip/hip_runtime.h>
#include <stdint.h>

#define PRIME 2013265921u
#define LOGN 21
#define NN (1u << LOGN)   // 2097152

// ---------- compile-time modular helpers ----------
constexpr uint32_t cpow(uint64_t b, uint64_t e) {
    uint64_t r = 1;
    b %= PRIME;
    while (e) {
        if (e & 1ull) r = r * b % PRIME;
        b = b * b % PRIME;
        e >>= 1;
    }
    return (uint32_t)r;
}
constexpr uint32_t cpinv() {           // PRIME^{-1} mod 2^32 (Newton)
    uint32_t inv = 1;
    for (int i = 0; i < 6; i++) inv *= 2u - PRIME * inv;
    return inv;
}
constexpr uint32_t NPRIME   = (uint32_t)(0u - cpinv());            // -P^{-1} mod 2^32
constexpr uint32_t RMODP    = (uint32_t)((1ull << 32) % PRIME);    // Mont(1)
constexpr uint32_t ROOT     = cpow(31u, (PRIME - 1) / NN);
constexpr uint32_t IROOT    = cpow(ROOT, PRIME - 2);
constexpr uint32_t IROOT1K  = cpow(IROOT, 1024);
constexpr uint32_t NINV     = cpow(NN, PRIME - 2);
constexpr uint32_t NINV_M   = (uint32_t)((((uint64_t)NINV) << 32) % PRIME);  // Mont(N^-1)

// ---------- modular arithmetic ----------
__device__ __forceinline__ uint32_t addmod(uint32_t a, uint32_t b) {
    uint32_t s = a + b; return (s >= PRIME) ? s - PRIME : s;
}
__device__ __forceinline__ uint32_t submod(uint32_t a, uint32_t b) {
    return (a >= b) ? (a - b) : (a + PRIME - b);
}
__device__ __forceinline__ uint32_t mulmod(uint32_t a, uint32_t b) {
    return (uint32_t)(((uint64_t)a * (uint64_t)b) % PRIME);
}
// Montgomery: montmul(a_normal, Mont(b)) = a*b mod P; montmul(Mont(a),Mont(b)) = Mont(ab)
__device__ __forceinline__ uint32_t montmul(uint32_t a, uint32_t b) {
    uint64_t t = (uint64_t)a * b;
    uint32_t m = (uint32_t)t * NPRIME;
    uint32_t u = (uint32_t)((t + (uint64_t)m * PRIME) >> 32);
    return (u >= PRIME) ? u - PRIME : u;
}
__device__ uint32_t powmod(uint32_t b, uint32_t e) {
    uint32_t r = 1u;
    while (e) {
        if (e & 1u) r = mulmod(r, b);
        b = mulmod(b, b);
        e >>= 1;
    }
    return r;
}
__device__ __forceinline__ uint32_t tomont(uint32_t x) {
    return (uint32_t)((((uint64_t)x) << 32) % PRIME);
}

// ---------- twiddles: A[i]=Mont(iroot^(1024 i)), B[i]=Mont(iroot^i), i<1024 ----------
__global__ void twiddle_ab_kernel(uint32_t* __restrict__ A, uint32_t* __restrict__ B) {
    uint32_t i = blockIdx.x * blockDim.x + threadIdx.x;   // < 1024
    B[i] = tomont(powmod(IROOT, i));
    A[i] = tomont(powmod(IROOT1K, i));
}
// Stage-packed table: Wfull[2^s + j] = Mont(iroot^(j << (20 - s))), j < 2^s, s=0..20
__global__ void twiddle_fill_kernel(const uint32_t* __restrict__ A, const uint32_t* __restrict__ B,
                                    uint32_t* __restrict__ Wfull) {
    uint32_t idx = blockIdx.x * blockDim.x + threadIdx.x;   // < 2^21
    if (idx == 0) { Wfull[0] = RMODP; return; }
    uint32_t s = 31u - __clz(idx);
    uint32_t j = idx ^ (1u << s);
    uint32_t e = j << (20u - s);                 // < 2^20
    Wfull[idx] = montmul(A[e >> 10], B[e & 1023u]);
}

// ---------- compress + fused coarse (64-bucket) histogram ----------
__global__ __launch_bounds__(256) void compress_kernel(
        const int* __restrict__ wl, const int* __restrict__ wr,
        const int* __restrict__ wo, const int* __restrict__ w4,
        const int* __restrict__ t1, const int* __restrict__ t2,
        const int* __restrict__ t3, const int* __restrict__ t4,
        const int* __restrict__ q,  const int* __restrict__ zp,
        uint32_t* __restrict__ tcomp, uint32_t* __restrict__ fcomp,
        unsigned int* __restrict__ hist64) {
    __shared__ unsigned int h64[64];
    if (threadIdx.x < 64) h64[threadIdx.x] = 0;
    __syncthreads();
    uint32_t z1 = ((uint32_t)zp[0]) % PRIME;
    uint32_t z2 = mulmod(z1, z1);
    uint32_t z3 = mulmod(z2, z1);
    for (uint32_t i = blockIdx.x * blockDim.x + threadIdx.x; i < NN; i += gridDim.x * blockDim.x) {
        uint32_t t = addmod(addmod((uint32_t)t1[i], mulmod((uint32_t)t2[i], z1)),
                            addmod(mulmod((uint32_t)t3[i], z2), mulmod((uint32_t)t4[i], z3)));
        uint32_t w = addmod(addmod((uint32_t)wl[i], mulmod((uint32_t)wr[i], z1)),
                            addmod(mulmod((uint32_t)wo[i], z2), mulmod((uint32_t)w4[i], z3)));
        uint32_t f = (q[i] != 0) ? w : t;
        tcomp[i] = t;
        fcomp[i] = f;
        atomicAdd(&h64[t >> 25], 1u);
        atomicAdd(&h64[f >> 25], 1u);
    }
    __syncthreads();
    if (threadIdx.x < 64 && h64[threadIdx.x])
        atomicAdd(&hist64[threadIdx.x], h64[threadIdx.x]);
}

// ---------- sort ----------
#define NBUCK 8192

__global__ void scan64_kernel(const unsigned int* __restrict__ hist64,
                              unsigned int* __restrict__ cbase, unsigned int* __restrict__ ccursor) {
    if (threadIdx.x == 0) {
        unsigned int run = 0;
        for (int b = 0; b < 64; b++) { cbase[b] = run; ccursor[b] = run; run += hist64[b]; }
        cbase[64] = run;
    }
}

// pass 1: scatter into 64 coarse buckets with LDS grouping (coalesced run writes)
__global__ __launch_bounds__(256) void pass1_kernel(const uint32_t* __restrict__ tcomp,
                                                    const uint32_t* __restrict__ fcomp,
                                                    unsigned int* __restrict__ ccursor,
                                                    uint32_t* __restrict__ barr1) {
    __shared__ uint32_t grp[4096];
    __shared__ unsigned char grpb[4096];
    __shared__ unsigned int cnt[64], pref[64], curs[64], rbase[64];
    uint32_t base = blockIdx.x * 4096;    // grid 1024 covers 2NN exactly
    uint32_t tid = threadIdx.x;
    if (tid < 64) cnt[tid] = 0;
    __syncthreads();
    for (uint32_t l = tid; l < 4096; l += 256) {
        uint32_t gi = base + l;
        uint32_t v = (gi < NN) ? tcomp[gi] : fcomp[gi - NN];
        atomicAdd(&cnt[v >> 25], 1u);
    }
    __syncthreads();
    if (tid == 0) {
        unsigned int run = 0;
        for (int b = 0; b < 64; b++) { pref[b] = run; curs[b] = run; run += cnt[b]; }
    }
    __syncthreads();
    if (tid < 64 && cnt[tid]) rbase[tid] = atomicAdd(&ccursor[tid], cnt[tid]);
    for (uint32_t l = tid; l < 4096; l += 256) {
        uint32_t gi = base + l;
        uint32_t v = (gi < NN) ? tcomp[gi] : fcomp[gi - NN];
        uint32_t b = v >> 25;
        unsigned int p = atomicAdd(&curs[b], 1u);
        grp[p] = v; grpb[p] = (unsigned char)b;
    }
    __syncthreads();
    for (uint32_t l = tid; l < 4096; l += 256) {
        uint32_t b = grpb[l];
        barr1[rbase[b] + (l - pref[b])] = grp[l];
    }
}

// fine (8192-bucket) histogram from coarse-partitioned data
__global__ __launch_bounds__(256) void fine_hist_kernel(const uint32_t* __restrict__ barr1,
                                                        const unsigned int* __restrict__ cbase,
                                                        unsigned int* __restrict__ hist) {
    __shared__ unsigned int cnt[128];
    uint32_t tid = threadIdx.x;
    uint32_t reg = blockIdx.y;
    if (tid < 128) cnt[tid] = 0;
    __syncthreads();
    uint32_t lo = cbase[reg], hi = cbase[reg + 1];
    for (uint32_t i = lo + blockIdx.x * 256 + tid; i < hi; i += gridDim.x * 256)
        atomicAdd(&cnt[(barr1[i] >> 18) & 127u], 1u);
    __syncthreads();
    if (tid < 128 && cnt[tid]) atomicAdd(&hist[reg * 128 + tid], cnt[tid]);
}

__global__ void scan_kernel(const unsigned int* __restrict__ hist,
                            unsigned int* __restrict__ basearr, unsigned int* __restrict__ fcursor) {
    __shared__ unsigned int ls[256];
    int t = threadIdx.x;
    unsigned int local[32];
    unsigned int s = 0;
    for (int k = 0; k < 32; k++) { local[k] = hist[t * 32 + k]; s += local[k]; }
    ls[t] = s;
    __syncthreads();
    for (int off = 1; off < 256; off <<= 1) {
        unsigned int v = (t >= off) ? ls[t - off] : 0u;
        __syncthreads();
        ls[t] += v;
        __syncthreads();
    }
    unsigned int run = ls[t] - s;  // exclusive prefix
    for (int k = 0; k < 32; k++) {
        basearr[t * 32 + k] = run;
        fcursor[t * 32 + k] = run;
        run += local[k];
    }
    if (t == 255) basearr[NBUCK] = run;
}

// pass 2: within each coarse region, scatter into 128 fine buckets (LDS grouping)
__global__ __launch_bounds__(256) void pass2_kernel(const uint32_t* __restrict__ barr1,
                                                    const unsigned int* __restrict__ cbase,
                                                    unsigned int* __restrict__ fcursor,
                                                    uint32_t* __restrict__ barr2) {
    __shared__ uint32_t grp[4096];
    __shared__ unsigned char grpb[4096];
    __shared__ unsigned int cnt[128], pref[128], curs[128], rbase[128];
    uint32_t tid = threadIdx.x;
    uint32_t reg = blockIdx.y;
    uint32_t lo = cbase[reg], hi = cbase[reg + 1];
    for (uint32_t start = lo + blockIdx.x * 4096; start < hi; start += gridDim.x * 4096) {
        uint32_t n = min(4096u, hi - start);
        if (tid < 128) cnt[tid] = 0;
        __syncthreads();
        for (uint32_t l = tid; l < n; l += 256)
            atomicAdd(&cnt[(barr1[start + l] >> 18) & 127u], 1u);
        __syncthreads();
        if (tid == 0) {
            unsigned int run = 0;
            for (int b = 0; b < 128; b++) { pref[b] = run; curs[b] = run; run += cnt[b]; }
        }
        __syncthreads();
        if (tid < 128 && cnt[tid]) rbase[tid] = atomicAdd(&fcursor[reg * 128 + tid], cnt[tid]);
        for (uint32_t l = tid; l < n; l += 256) {
            uint32_t v = barr1[start + l];
            uint32_t b = (v >> 18) & 127u;
            unsigned int p = atomicAdd(&curs[b], 1u);
            grp[p] = v; grpb[p] = (unsigned char)b;
        }
        __syncthreads();
        for (uint32_t l = tid; l < n; l += 256) {
            uint32_t b = grpb[l];
            barr2[rbase[b] + (l - pref[b])] = grp[l];
        }
        __syncthreads();
    }
}

// ---------- per-bucket O(n) MSD counting sort ----------
__global__ __launch_bounds__(256) void bucket_sort_kernel(const uint32_t* __restrict__ barr,
                                                          const unsigned int* __restrict__ basearr,
                                                          uint32_t* __restrict__ h1, uint32_t* __restrict__ h2) {
    __shared__ uint32_t ord[4096];
    __shared__ unsigned int cnt[128], pref[128], curs[128];
    uint32_t b  = blockIdx.x;
    uint32_t lo = basearr[b], hi = basearr[b + 1];
    uint32_t n  = hi - lo;
    if (n == 0) return;
    if (n > 4096) n = 4096;   // unreachable for this distribution
    uint32_t tid = threadIdx.x;
    if (tid < 128) cnt[tid] = 0;
    __syncthreads();
    for (uint32_t i = tid; i < n; i += 256)
        atomicAdd(&cnt[(barr[lo + i] >> 11) & 127u], 1u);
    __syncthreads();
    if (tid == 0) {
        unsigned int run = 0;
        for (int d = 0; d < 128; d++) { pref[d] = run; curs[d] = run; run += cnt[d]; }
    }
    __syncthreads();
    for (uint32_t i = tid; i < n; i += 256) {
        uint32_t v = barr[lo + i];
        uint32_t d = (v >> 11) & 127u;
        unsigned int p = atomicAdd(&curs[d], 1u);
        ord[p] = v;
    }
    __syncthreads();
    for (uint32_t p = tid; p < n; p += 256) {
        uint32_t v = ord[p];
        uint32_t d = (v >> 11) & 127u;
        uint32_t l0 = pref[d], l1 = l0 + cnt[d];
        uint32_t r = 0;
        for (uint32_t q = l0; q < l1; q++) {
            uint32_t u = ord[q];
            r += (u < v) || (u == v && q < p);
        }
        uint32_t gp = lo + l0 + r;
        if (gp & 1) h2[gp >> 1] = v; else h1[gp >> 1] = v;
    }
}

// ---------- bit-reversal permute: dst[i] = src[rev21(i)], tiled ----------
struct SrcPtrs { const uint32_t* p[8]; };

__global__ void bitrev_kernel(SrcPtrs srcs, uint32_t* __restrict__ dst) {
    __shared__ uint32_t tile[64 * 65];
    uint32_t poly = blockIdx.y;
    const uint32_t* src = srcs.p[poly];
    uint32_t* out = dst + (size_t)poly * NN;
    uint32_t m  = blockIdx.x;                 // 9-bit middle
    uint32_t rm = __brev(m) >> 23;            // rev9
    for (uint32_t l = threadIdx.x; l < 4096; l += blockDim.x) {
        uint32_t u = l >> 6, v = l & 63;
        tile[u * 65 + v] = src[(u << 15) | (rm << 6) | v];
    }
    __syncthreads();
    for (uint32_t l = threadIdx.x; l < 4096; l += blockDim.x) {
        uint32_t a = l >> 6, b = l & 63;
        uint32_t ra = __brev(a) >> 26, rb = __brev(b) >> 26;  // rev6
        out[(a << 15) | (m << 6) | b] = tile[rb * 65 + ra];
    }
}

// ---------- NTT stages 1..12 in LDS; twiddles preloaded to LDS; n_inv folded in ----------
__device__ __forceinline__ uint32_t padi(uint32_t i) { return i + (i >> 5); }

__global__ __launch_bounds__(256) void ntt_phase1_kernel(uint32_t* __restrict__ polys,
                                                         const uint32_t* __restrict__ Wfull) {
    __shared__ uint32_t wt[4096];
    __shared__ uint32_t sd[4224];     // padded: i + (i>>5)
    uint32_t* x = polys + (size_t)blockIdx.y * NN + (size_t)blockIdx.x * 4096;
    for (uint32_t l = threadIdx.x; l < 4096; l += 256) {
        wt[l] = Wfull[l];
        sd[padi(l)] = x[l];
    }
    __syncthreads();
    for (int st = 1; st <= 12; st++) {
        uint32_t half = 1u << (st - 1);
        #pragma unroll 2
        for (uint32_t bf = threadIdx.x; bf < 2048; bf += 256) {
            uint32_t j  = bf & (half - 1);
            uint32_t g  = bf >> (st - 1);
            uint32_t i0 = (g << st) + j, i1 = i0 + half;
            uint32_t w = wt[half + j];
            uint32_t u = sd[padi(i0)];
            uint32_t v = montmul(sd[padi(i1)], w);
            sd[padi(i0)] = addmod(u, v);
            sd[padi(i1)] = submod(u, v);
        }
        __syncthreads();
    }
    // fold in N^-1 scaling here (linear, commutes with remaining stages)
    for (uint32_t l = threadIdx.x; l < 4096; l += 256)
        x[l] = montmul(sd[padi(l)], NINV_M);
}

// ---------- NTT stages 13..21 + fused commit partial sums; float output ----------
__device__ __forceinline__ uint32_t pad16(uint32_t idx) { return idx + (idx >> 5); }

__global__ __launch_bounds__(256) void ntt_phase2_kernel(uint32_t* __restrict__ polys,
                                                         const uint32_t* __restrict__ Wfull,
                                                         const float* __restrict__ g,
                                                         double* __restrict__ partials) {
    __shared__ uint32_t sd[8448];     // 8192 data + pad
    __shared__ uint32_t rowt[512];    // rowt[hb+kk] = Mont(iroot^(kk·4096 << (8-s)))
    __shared__ double red[256];
    uint32_t* x = polys + (size_t)blockIdx.y * NN;
    uint32_t c0 = blockIdx.x * 16;
    uint32_t tid = threadIdx.x;
    uint32_t c = tid & 15u;
    uint32_t rt = tid >> 4;           // 0..15

    for (uint32_t l = tid; l < 8192; l += 256) {
        uint32_t b = l >> 4, cc = l & 15;
        sd[pad16(l)] = x[c0 + cc + (b << 12)];
    }
    rowt[tid]       = (tid == 0) ? RMODP : Wfull[tid << 12];
    rowt[tid + 256] = Wfull[(uint32_t)(tid + 256) << 12];
    uint32_t cw[9];
    #pragma unroll
    for (int s = 0; s < 9; s++) cw[s] = Wfull[(1u << (12 + s)) + c0 + c];
    __syncthreads();

    #pragma unroll
    for (int s = 0; s < 9; s++) {     // stage st = 13 + s
        uint32_t hb = 1u << s;
        #pragma unroll 4
        for (uint32_t m = 0; m < 16; m++) {
            uint32_t p  = (rt << 4) + m;          // pair index 0..255
            uint32_t kk = p & (hb - 1);
            uint32_t gg = p >> s;
            uint32_t b0 = (gg << (s + 1)) + kk, b1 = b0 + hb;
            uint32_t w = montmul(rowt[hb + kk], cw[s]);
            uint32_t i0 = pad16((b0 << 4) + c), i1 = pad16((b1 << 4) + c);
            uint32_t u = sd[i0];
            uint32_t v = montmul(sd[i1], w);
            sd[i0] = addmod(u, v);
            sd[i1] = submod(u, v);
        }
        __syncthreads();
    }

    // epilogue: write FINAL float values + fused commit partial accumulation
    float* xf = (float*)x;
    const float invp = (float)(1.0 / 2013265921.0);
    double a0 = 0.0, a1 = 0.0, a2 = 0.0;
    for (uint32_t l = tid; l < 8192; l += 256) {
        uint32_t b = l >> 4, cc = l & 15;
        uint32_t idx = c0 + cc + (b << 12);
        float fv = (float)sd[pad16(l)];
        xf[idx] = fv;
        float s = fv * invp;
        a0 += (double)(s * g[idx * 3 + 0]);
        a1 += (double)(s * g[idx * 3 + 1]);
        a2 += (double)(s * g[idx * 3 + 2]);
    }
    double v3[3] = {a0, a1, a2};
    #pragma unroll
    for (int k = 0; k < 3; k++) {
        __syncthreads();
        red[tid] = v3[k];
        __syncthreads();
        for (int off = 128; off > 0; off >>= 1) {
            if (tid < off) red[tid] += red[tid + off];
            __syncthreads();
        }
        if (tid == 0) partials[((size_t)blockIdx.y * 256 + blockIdx.x) * 3 + k] = red[0];
    }
}

// ---------- final commit reduce: 8 polys x 256 blocks x 3 comps -> 24 floats ----------
__global__ void reduce_commits_kernel(const double* __restrict__ partials, float* __restrict__ outf) {
    __shared__ double red[256];
    int t = threadIdx.x;
    for (int k = 0; k < 24; k++) {
        int p = k / 3, cc = k % 3;
        red[t] = partials[((size_t)p * 256 + t) * 3 + cc];
        __syncthreads();
        for (int off = 128; off > 0; off >>= 1) {
            if (t < off) red[t] += red[t + off];
            __syncthreads();
        }
        if (t == 0) outf[k] = (float)red[0];
        __syncthreads();
    }
}

extern "C" void kernel_launch(void* const* d_in, const int* in_sizes, int n_in,
                              void* d_out, int out_size, void* d_ws, size_t ws_size,
                              hipStream_t stream) {
    const int* wl = (const int*)d_in[0];
    const int* wr = (const int*)d_in[1];
    const int* wo = (const int*)d_in[2];
    const int* w4 = (const int*)d_in[3];
    const int* t1 = (const int*)d_in[4];
    const int* t2 = (const int*)d_in[5];
    const int* t3 = (const int*)d_in[6];
    const int* t4 = (const int*)d_in[7];
    const int* q  = (const int*)d_in[8];
    const float* g = (const float*)d_in[9];
    const int* zp = (const int*)d_in[10];

    char* ws = (char*)d_ws;
    uint32_t* Wfull  = (uint32_t*)(ws);                       // 8 MB
    uint32_t* tcomp  = (uint32_t*)(ws + (8ull  << 20));       // 8 MB
    uint32_t* fcomp  = (uint32_t*)(ws + (16ull << 20));       // 8 MB
    uint32_t* h1     = (uint32_t*)(ws + (24ull << 20));       // 8 MB
    uint32_t* h2     = (uint32_t*)(ws + (32ull << 20));       // 8 MB
    // small buffers at 64 KiB-aligned offsets
    unsigned int* hist    = (unsigned int*)(ws + (40ull << 20));                  // 32 KB
    unsigned int* basearr = (unsigned int*)(ws + (40ull << 20) + (64u  << 10));   // 32 KB+4
    unsigned int* fcursor = (unsigned int*)(ws + (40ull << 20) + (128u << 10));   // 32 KB
    uint32_t*     tA      = (uint32_t*)   (ws + (40ull << 20) + (200u << 10));    // 4 KB
    uint32_t*     tB      = (uint32_t*)   (ws + (40ull << 20) + (208u << 10));    // 4 KB
    unsigned int* hist64  = (unsigned int*)(ws + (40ull << 20) + (216u << 10));   // 256 B
    unsigned int* cbase   = (unsigned int*)(ws + (40ull << 20) + (224u << 10));   // 260 B
    unsigned int* ccursor = (unsigned int*)(ws + (40ull << 20) + (232u << 10));   // 256 B
    double*       partials = (double*)    (ws + (40ull << 20) + (256u << 10));    // 48 KB (8-aligned)

    float* outf = (float*)d_out;
    uint32_t* outpolys = (uint32_t*)outf + 24;                      // 8*N, final floats
    uint32_t* barr1 = (uint32_t*)outf + 1024;                       // 16 MB scratch (pre-NTT)
    uint32_t* barr2 = (uint32_t*)outf + 1024 + (5u << 20);          // 16 MB scratch (pre-NTT)

    hipMemsetAsync(hist, 0, NBUCK * sizeof(unsigned int), stream);
    hipMemsetAsync(hist64, 0, 64 * sizeof(unsigned int), stream);

    twiddle_ab_kernel<<<4, 256, 0, stream>>>(tA, tB);
    twiddle_fill_kernel<<<NN / 256, 256, 0, stream>>>(tA, tB, Wfull);

    compress_kernel<<<2048, 256, 0, stream>>>(wl, wr, wo, w4, t1, t2, t3, t4, q, zp,
                                              tcomp, fcomp, hist64);
    scan64_kernel<<<1, 64, 0, stream>>>(hist64, cbase, ccursor);
    pass1_kernel<<<1024, 256, 0, stream>>>(tcomp, fcomp, ccursor, barr1);
    fine_hist_kernel<<<dim3(16, 64), 256, 0, stream>>>(barr1, cbase, hist);
    scan_kernel<<<1, 256, 0, stream>>>(hist, basearr, fcursor);
    pass2_kernel<<<dim3(16, 64), 256, 0, stream>>>(barr1, cbase, fcursor, barr2);
    bucket_sort_kernel<<<NBUCK, 256, 0, stream>>>(barr2, basearr, h1, h2);

    SrcPtrs sp;
    sp.p[0] = (const uint32_t*)wl;
    sp.p[1] = (const uint32_t*)wr;
    sp.p[2] = (const uint32_t*)wo;
    sp.p[3] = (const uint32_t*)w4;
    sp.p[4] = tcomp;
    sp.p[5] = fcomp;
    sp.p[6] = h1;
    sp.p[7] = h2;
    bitrev_kernel<<<dim3(512, 8), 256, 0, stream>>>(sp, outpolys);
    ntt_phase1_kernel<<<dim3(512, 8), 256, 0, stream>>>(outpolys, Wfull);
    ntt_phase2_kernel<<<dim3(256, 8), 256, 0, stream>>>(outpolys, Wfull, g, partials);

    reduce_commits_kernel<<<1, 256, 0, stream>>>(partials, outf);
}

// Round 8
// 379.583 us; speedup vs baseline: 3.6406x; 1.0208x over previous
//
#include <hip/hip_runtime.h>
#include <stdint.h>

#define PRIME 2013265921u
#define LOGN 21
#define NN (1u << LOGN)   // 2097152

// ---------- compile-time modular helpers ----------
constexpr uint32_t cpow(uint64_t b, uint64_t e) {
    uint64_t r = 1;
    b %= PRIME;
    while (e) {
        if (e & 1ull) r = r * b % PRIME;
        b = b * b % PRIME;
        e >>= 1;
    }
    return (uint32_t)r;
}
constexpr uint32_t cpinv() {           // PRIME^{-1} mod 2^32 (Newton)
    uint32_t inv = 1;
    for (int i = 0; i < 6; i++) inv *= 2u - PRIME * inv;
    return inv;
}
constexpr uint32_t NPRIME   = (uint32_t)(0u - cpinv());            // -P^{-1} mod 2^32
constexpr uint32_t RMODP    = (uint32_t)((1ull << 32) % PRIME);    // Mont(1)
constexpr uint32_t ROOT     = cpow(31u, (PRIME - 1) / NN);
constexpr uint32_t IROOT    = cpow(ROOT, PRIME - 2);
constexpr uint32_t IROOT1K  = cpow(IROOT, 1024);
constexpr uint32_t NINV     = cpow(NN, PRIME - 2);
constexpr uint32_t NINV_M   = (uint32_t)((((uint64_t)NINV) << 32) % PRIME);  // Mont(N^-1)

// ---------- modular arithmetic ----------
__device__ __forceinline__ uint32_t addmod(uint32_t a, uint32_t b) {
    uint32_t s = a + b; return (s >= PRIME) ? s - PRIME : s;
}
__device__ __forceinline__ uint32_t submod(uint32_t a, uint32_t b) {
    return (a >= b) ? (a - b) : (a + PRIME - b);
}
__device__ __forceinline__ uint32_t mulmod(uint32_t a, uint32_t b) {
    return (uint32_t)(((uint64_t)a * (uint64_t)b) % PRIME);
}
// Montgomery: montmul(a_normal, Mont(b)) = a*b mod P; montmul(Mont(a),Mont(b)) = Mont(ab)
__device__ __forceinline__ uint32_t montmul(uint32_t a, uint32_t b) {
    uint64_t t = (uint64_t)a * b;
    uint32_t m = (uint32_t)t * NPRIME;
    uint32_t u = (uint32_t)((t + (uint64_t)m * PRIME) >> 32);
    return (u >= PRIME) ? u - PRIME : u;
}
__device__ uint32_t powmod(uint32_t b, uint32_t e) {
    uint32_t r = 1u;
    while (e) {
        if (e & 1u) r = mulmod(r, b);
        b = mulmod(b, b);
        e >>= 1;
    }
    return r;
}
__device__ __forceinline__ uint32_t tomont(uint32_t x) {
    return (uint32_t)((((uint64_t)x) << 32) % PRIME);
}

// ---------- twiddles: A[i]=Mont(iroot^(1024 i)), B[i]=Mont(iroot^i), i<1024 ----------
__global__ void twiddle_ab_kernel(uint32_t* __restrict__ A, uint32_t* __restrict__ B) {
    uint32_t i = blockIdx.x * blockDim.x + threadIdx.x;   // < 1024
    B[i] = tomont(powmod(IROOT, i));
    A[i] = tomont(powmod(IROOT1K, i));
}
// Stage-packed table: Wfull[2^s + j] = Mont(iroot^(j << (20 - s))), j < 2^s, s=0..20
__global__ void twiddle_fill_kernel(const uint32_t* __restrict__ A, const uint32_t* __restrict__ B,
                                    uint32_t* __restrict__ Wfull) {
    uint32_t idx = blockIdx.x * blockDim.x + threadIdx.x;   // < 2^21
    if (idx == 0) { Wfull[0] = RMODP; return; }
    uint32_t s = 31u - __clz(idx);
    uint32_t j = idx ^ (1u << s);
    uint32_t e = j << (20u - s);                 // < 2^20
    Wfull[idx] = montmul(A[e >> 10], B[e & 1023u]);
}

// ---------- compress + fused coarse (64-bucket) histogram ----------
__global__ __launch_bounds__(256) void compress_kernel(
        const int* __restrict__ wl, const int* __restrict__ wr,
        const int* __restrict__ wo, const int* __restrict__ w4,
        const int* __restrict__ t1, const int* __restrict__ t2,
        const int* __restrict__ t3, const int* __restrict__ t4,
        const int* __restrict__ q,  const int* __restrict__ zp,
        uint32_t* __restrict__ tcomp, uint32_t* __restrict__ fcomp,
        unsigned int* __restrict__ hist64) {
    __shared__ unsigned int h64[64];
    if (threadIdx.x < 64) h64[threadIdx.x] = 0;
    __syncthreads();
    uint32_t z1 = ((uint32_t)zp[0]) % PRIME;
    uint32_t z2 = mulmod(z1, z1);
    uint32_t z3 = mulmod(z2, z1);
    for (uint32_t i = blockIdx.x * blockDim.x + threadIdx.x; i < NN; i += gridDim.x * blockDim.x) {
        uint32_t t = addmod(addmod((uint32_t)t1[i], mulmod((uint32_t)t2[i], z1)),
                            addmod(mulmod((uint32_t)t3[i], z2), mulmod((uint32_t)t4[i], z3)));
        uint32_t w = addmod(addmod((uint32_t)wl[i], mulmod((uint32_t)wr[i], z1)),
                            addmod(mulmod((uint32_t)wo[i], z2), mulmod((uint32_t)w4[i], z3)));
        uint32_t f = (q[i] != 0) ? w : t;
        tcomp[i] = t;
        fcomp[i] = f;
        atomicAdd(&h64[t >> 25], 1u);
        atomicAdd(&h64[f >> 25], 1u);
    }
    __syncthreads();
    if (threadIdx.x < 64 && h64[threadIdx.x])
        atomicAdd(&hist64[threadIdx.x], h64[threadIdx.x]);
}

// ---------- sort ----------
#define NBUCK 8192

__global__ void scan64_kernel(const unsigned int* __restrict__ hist64,
                              unsigned int* __restrict__ cbase, unsigned int* __restrict__ ccursor) {
    if (threadIdx.x == 0) {
        unsigned int run = 0;
        for (int b = 0; b < 64; b++) { cbase[b] = run; ccursor[b] = run; run += hist64[b]; }
        cbase[64] = run;
    }
}

// pass 1: scatter into 64 coarse buckets with LDS grouping (coalesced run writes)
__global__ __launch_bounds__(256) void pass1_kernel(const uint32_t* __restrict__ tcomp,
                                                    const uint32_t* __restrict__ fcomp,
                                                    unsigned int* __restrict__ ccursor,
                                                    uint32_t* __restrict__ barr1) {
    __shared__ uint32_t grp[4096];
    __shared__ unsigned char grpb[4096];
    __shared__ unsigned int cnt[64], pref[64], curs[64], rbase[64];
    uint32_t base = blockIdx.x * 4096;    // grid 1024 covers 2NN exactly
    uint32_t tid = threadIdx.x;
    if (tid < 64) cnt[tid] = 0;
    __syncthreads();
    for (uint32_t l = tid; l < 4096; l += 256) {
        uint32_t gi = base + l;
        uint32_t v = (gi < NN) ? tcomp[gi] : fcomp[gi - NN];
        atomicAdd(&cnt[v >> 25], 1u);
    }
    __syncthreads();
    if (tid == 0) {
        unsigned int run = 0;
        for (int b = 0; b < 64; b++) { pref[b] = run; curs[b] = run; run += cnt[b]; }
    }
    __syncthreads();
    if (tid < 64 && cnt[tid]) rbase[tid] = atomicAdd(&ccursor[tid], cnt[tid]);
    for (uint32_t l = tid; l < 4096; l += 256) {
        uint32_t gi = base + l;
        uint32_t v = (gi < NN) ? tcomp[gi] : fcomp[gi - NN];
        uint32_t b = v >> 25;
        unsigned int p = atomicAdd(&curs[b], 1u);
        grp[p] = v; grpb[p] = (unsigned char)b;
    }
    __syncthreads();
    for (uint32_t l = tid; l < 4096; l += 256) {
        uint32_t b = grpb[l];
        barr1[rbase[b] + (l - pref[b])] = grp[l];
    }
}

// fine (8192-bucket) histogram from coarse-partitioned data
__global__ __launch_bounds__(256) void fine_hist_kernel(const uint32_t* __restrict__ barr1,
                                                        const unsigned int* __restrict__ cbase,
                                                        unsigned int* __restrict__ hist) {
    __shared__ unsigned int cnt[128];
    uint32_t tid = threadIdx.x;
    uint32_t reg = blockIdx.y;
    if (tid < 128) cnt[tid] = 0;
    __syncthreads();
    uint32_t lo = cbase[reg], hi = cbase[reg + 1];
    for (uint32_t i = lo + blockIdx.x * 256 + tid; i < hi; i += gridDim.x * 256)
        atomicAdd(&cnt[(barr1[i] >> 18) & 127u], 1u);
    __syncthreads();
    if (tid < 128 && cnt[tid]) atomicAdd(&hist[reg * 128 + tid], cnt[tid]);
}

__global__ void scan_kernel(const unsigned int* __restrict__ hist,
                            unsigned int* __restrict__ basearr, unsigned int* __restrict__ fcursor) {
    __shared__ unsigned int ls[256];
    int t = threadIdx.x;
    unsigned int local[32];
    unsigned int s = 0;
    for (int k = 0; k < 32; k++) { local[k] = hist[t * 32 + k]; s += local[k]; }
    ls[t] = s;
    __syncthreads();
    for (int off = 1; off < 256; off <<= 1) {
        unsigned int v = (t >= off) ? ls[t - off] : 0u;
        __syncthreads();
        ls[t] += v;
        __syncthreads();
    }
    unsigned int run = ls[t] - s;  // exclusive prefix
    for (int k = 0; k < 32; k++) {
        basearr[t * 32 + k] = run;
        fcursor[t * 32 + k] = run;
        run += local[k];
    }
    if (t == 255) basearr[NBUCK] = run;
}

// pass 2: within each coarse region, scatter into 128 fine buckets (LDS grouping)
__global__ __launch_bounds__(256) void pass2_kernel(const uint32_t* __restrict__ barr1,
                                                    const unsigned int* __restrict__ cbase,
                                                    unsigned int* __restrict__ fcursor,
                                                    uint32_t* __restrict__ barr2) {
    __shared__ uint32_t grp[4096];
    __shared__ unsigned char grpb[4096];
    __shared__ unsigned int cnt[128], pref[128], curs[128], rbase[128];
    uint32_t tid = threadIdx.x;
    uint32_t reg = blockIdx.y;
    uint32_t lo = cbase[reg], hi = cbase[reg + 1];
    for (uint32_t start = lo + blockIdx.x * 4096; start < hi; start += gridDim.x * 4096) {
        uint32_t n = min(4096u, hi - start);
        if (tid < 128) cnt[tid] = 0;
        __syncthreads();
        for (uint32_t l = tid; l < n; l += 256)
            atomicAdd(&cnt[(barr1[start + l] >> 18) & 127u], 1u);
        __syncthreads();
        if (tid == 0) {
            unsigned int run = 0;
            for (int b = 0; b < 128; b++) { pref[b] = run; curs[b] = run; run += cnt[b]; }
        }
        __syncthreads();
        if (tid < 128 && cnt[tid]) rbase[tid] = atomicAdd(&fcursor[reg * 128 + tid], cnt[tid]);
        for (uint32_t l = tid; l < n; l += 256) {
            uint32_t v = barr1[start + l];
            uint32_t b = (v >> 18) & 127u;
            unsigned int p = atomicAdd(&curs[b], 1u);
            grp[p] = v; grpb[p] = (unsigned char)b;
        }
        __syncthreads();
        for (uint32_t l = tid; l < n; l += 256) {
            uint32_t b = grpb[l];
            barr2[rbase[b] + (l - pref[b])] = grp[l];
        }
        __syncthreads();
    }
}

// ---------- per-bucket O(n) MSD counting sort ----------
__global__ __launch_bounds__(256) void bucket_sort_kernel(const uint32_t* __restrict__ barr,
                                                          const unsigned int* __restrict__ basearr,
                                                          uint32_t* __restrict__ h1, uint32_t* __restrict__ h2) {
    __shared__ uint32_t ord[4096];
    __shared__ unsigned int cnt[128], pref[128], curs[128];
    uint32_t b  = blockIdx.x;
    uint32_t lo = basearr[b], hi = basearr[b + 1];
    uint32_t n  = hi - lo;
    if (n == 0) return;
    if (n > 4096) n = 4096;   // unreachable for this distribution
    uint32_t tid = threadIdx.x;
    if (tid < 128) cnt[tid] = 0;
    __syncthreads();
    for (uint32_t i = tid; i < n; i += 256)
        atomicAdd(&cnt[(barr[lo + i] >> 11) & 127u], 1u);
    __syncthreads();
    if (tid == 0) {
        unsigned int run = 0;
        for (int d = 0; d < 128; d++) { pref[d] = run; curs[d] = run; run += cnt[d]; }
    }
    __syncthreads();
    for (uint32_t i = tid; i < n; i += 256) {
        uint32_t v = barr[lo + i];
        uint32_t d = (v >> 11) & 127u;
        unsigned int p = atomicAdd(&curs[d], 1u);
        ord[p] = v;
    }
    __syncthreads();
    for (uint32_t p = tid; p < n; p += 256) {
        uint32_t v = ord[p];
        uint32_t d = (v >> 11) & 127u;
        uint32_t l0 = pref[d], l1 = l0 + cnt[d];
        uint32_t r = 0;
        for (uint32_t q = l0; q < l1; q++) {
            uint32_t u = ord[q];
            r += (u < v) || (u == v && q < p);
        }
        uint32_t gp = lo + l0 + r;
        if (gp & 1) h2[gp >> 1] = v; else h1[gp >> 1] = v;
    }
}

// ---------- bit-reversal permute: dst[i] = src[rev21(i)], tiled ----------
struct SrcPtrs { const uint32_t* p[8]; };

__global__ void bitrev_kernel(SrcPtrs srcs, uint32_t* __restrict__ dst) {
    __shared__ uint32_t tile[64 * 65];
    uint32_t poly = blockIdx.y;
    const uint32_t* src = srcs.p[poly];
    uint32_t* out = dst + (size_t)poly * NN;
    uint32_t m  = blockIdx.x;                 // 9-bit middle
    uint32_t rm = __brev(m) >> 23;            // rev9
    for (uint32_t l = threadIdx.x; l < 4096; l += blockDim.x) {
        uint32_t u = l >> 6, v = l & 63;
        tile[u * 65 + v] = src[(u << 15) | (rm << 6) | v];
    }
    __syncthreads();
    for (uint32_t l = threadIdx.x; l < 4096; l += blockDim.x) {
        uint32_t a = l >> 6, b = l & 63;
        uint32_t ra = __brev(a) >> 26, rb = __brev(b) >> 26;  // rev6
        out[(a << 15) | (m << 6) | b] = tile[rb * 65 + ra];
    }
}

// ---------- NTT stages 1..12 in LDS; twiddles preloaded to LDS; n_inv folded in ----------
__device__ __forceinline__ uint32_t padi(uint32_t i) { return i + (i >> 5); }

__global__ __launch_bounds__(256) void ntt_phase1_kernel(uint32_t* __restrict__ polys,
                                                         const uint32_t* __restrict__ Wfull) {
    __shared__ uint32_t wt[4096];
    __shared__ uint32_t sd[4224];     // padded: i + (i>>5)
    uint32_t* x = polys + (size_t)blockIdx.y * NN + (size_t)blockIdx.x * 4096;
    for (uint32_t l = threadIdx.x; l < 4096; l += 256) {
        wt[l] = Wfull[l];
        sd[padi(l)] = x[l];
    }
    __syncthreads();
    for (int st = 1; st <= 12; st++) {
        uint32_t half = 1u << (st - 1);
        #pragma unroll 2
        for (uint32_t bf = threadIdx.x; bf < 2048; bf += 256) {
            uint32_t j  = bf & (half - 1);
            uint32_t g  = bf >> (st - 1);
            uint32_t i0 = (g << st) + j, i1 = i0 + half;
            uint32_t w = wt[half + j];
            uint32_t u = sd[padi(i0)];
            uint32_t v = montmul(sd[padi(i1)], w);
            sd[padi(i0)] = addmod(u, v);
            sd[padi(i1)] = submod(u, v);
        }
        __syncthreads();
    }
    // fold in N^-1 scaling here (linear, commutes with remaining stages)
    for (uint32_t l = threadIdx.x; l < 4096; l += 256)
        x[l] = montmul(sd[padi(l)], NINV_M);
}

// ---------- NTT stages 13..21 + fused commit partials; XCD-aware block remap ----------
__device__ __forceinline__ uint32_t pad16(uint32_t idx) { return idx + (idx >> 5); }

__global__ __launch_bounds__(256) void ntt_phase2_kernel(uint32_t* __restrict__ polys,
                                                         const uint32_t* __restrict__ Wfull,
                                                         const float* __restrict__ g,
                                                         double* __restrict__ partials) {
    __shared__ uint32_t sd[8448];     // 8192 data + pad
    __shared__ uint32_t rowt[512];    // rowt[hb+kk] = Mont(iroot^(kk·4096 << (8-s)))
    __shared__ double red[256];
    // XCD-aware remap: blocks round-robin XCDs by linear id. Group the 8 polys of
    // one c0-slice onto ONE XCD consecutively so they share the g-slice in its L2.
    uint32_t b = blockIdx.x;              // 0..2047
    uint32_t xcd = b & 7u, k = b >> 3;    // k: 0..255
    uint32_t c0_idx = xcd * 32u + (k >> 3);
    uint32_t poly = k & 7u;
    uint32_t* x = polys + (size_t)poly * NN;
    uint32_t c0 = c0_idx * 16u;
    uint32_t tid = threadIdx.x;
    uint32_t c = tid & 15u;
    uint32_t rt = tid >> 4;           // 0..15

    for (uint32_t l = tid; l < 8192; l += 256) {
        uint32_t bb = l >> 4, cc = l & 15;
        sd[pad16(l)] = x[c0 + cc + (bb << 12)];
    }
    rowt[tid]       = (tid == 0) ? RMODP : Wfull[tid << 12];
    rowt[tid + 256] = Wfull[(uint32_t)(tid + 256) << 12];
    uint32_t cw[9];
    #pragma unroll
    for (int s = 0; s < 9; s++) cw[s] = Wfull[(1u << (12 + s)) + c0 + c];
    __syncthreads();

    #pragma unroll
    for (int s = 0; s < 9; s++) {     // stage st = 13 + s
        uint32_t hb = 1u << s;
        #pragma unroll 4
        for (uint32_t m = 0; m < 16; m++) {
            uint32_t p  = (rt << 4) + m;          // pair index 0..255
            uint32_t kk = p & (hb - 1);
            uint32_t gg = p >> s;
            uint32_t b0 = (gg << (s + 1)) + kk, b1 = b0 + hb;
            uint32_t w = montmul(rowt[hb + kk], cw[s]);
            uint32_t i0 = pad16((b0 << 4) + c), i1 = pad16((b1 << 4) + c);
            uint32_t u = sd[i0];
            uint32_t v = montmul(sd[i1], w);
            sd[i0] = addmod(u, v);
            sd[i1] = submod(u, v);
        }
        __syncthreads();
    }

    // epilogue: final float values (nontemporal: never re-read) + commit partials
    float* xf = (float*)x;
    const float invp = (float)(1.0 / 2013265921.0);
    double a0 = 0.0, a1 = 0.0, a2 = 0.0;
    for (uint32_t l = tid; l < 8192; l += 256) {
        uint32_t bb = l >> 4, cc = l & 15;
        uint32_t idx = c0 + cc + (bb << 12);
        float fv = (float)sd[pad16(l)];
        __builtin_nontemporal_store(fv, &xf[idx]);
        float s = fv * invp;
        a0 += (double)(s * g[idx * 3 + 0]);
        a1 += (double)(s * g[idx * 3 + 1]);
        a2 += (double)(s * g[idx * 3 + 2]);
    }
    double v3[3] = {a0, a1, a2};
    #pragma unroll
    for (int kq = 0; kq < 3; kq++) {
        __syncthreads();
        red[tid] = v3[kq];
        __syncthreads();
        for (int off = 128; off > 0; off >>= 1) {
            if (tid < off) red[tid] += red[tid + off];
            __syncthreads();
        }
        if (tid == 0) partials[((size_t)poly * 256 + c0_idx) * 3 + kq] = red[0];
    }
}

// ---------- final commit reduce: 8 polys x 256 blocks x 3 comps -> 24 floats ----------
__global__ void reduce_commits_kernel(const double* __restrict__ partials, float* __restrict__ outf) {
    __shared__ double red[256];
    int t = threadIdx.x;
    for (int k = 0; k < 24; k++) {
        int p = k / 3, cc = k % 3;
        red[t] = partials[((size_t)p * 256 + t) * 3 + cc];
        __syncthreads();
        for (int off = 128; off > 0; off >>= 1) {
            if (t < off) red[t] += red[t + off];
            __syncthreads();
        }
        if (t == 0) outf[k] = (float)red[0];
        __syncthreads();
    }
}

extern "C" void kernel_launch(void* const* d_in, const int* in_sizes, int n_in,
                              void* d_out, int out_size, void* d_ws, size_t ws_size,
                              hipStream_t stream) {
    const int* wl = (const int*)d_in[0];
    const int* wr = (const int*)d_in[1];
    const int* wo = (const int*)d_in[2];
    const int* w4 = (const int*)d_in[3];
    const int* t1 = (const int*)d_in[4];
    const int* t2 = (const int*)d_in[5];
    const int* t3 = (const int*)d_in[6];
    const int* t4 = (const int*)d_in[7];
    const int* q  = (const int*)d_in[8];
    const float* g = (const float*)d_in[9];
    const int* zp = (const int*)d_in[10];

    char* ws = (char*)d_ws;
    uint32_t* Wfull  = (uint32_t*)(ws);                       // 8 MB
    uint32_t* tcomp  = (uint32_t*)(ws + (8ull  << 20));       // 8 MB
    uint32_t* fcomp  = (uint32_t*)(ws + (16ull << 20));       // 8 MB
    uint32_t* h1     = (uint32_t*)(ws + (24ull << 20));       // 8 MB
    uint32_t* h2     = (uint32_t*)(ws + (32ull << 20));       // 8 MB
    // small buffers at 64 KiB-aligned offsets
    unsigned int* hist    = (unsigned int*)(ws + (40ull << 20));                  // 32 KB
    unsigned int* basearr = (unsigned int*)(ws + (40ull << 20) + (64u  << 10));   // 32 KB+4
    unsigned int* fcursor = (unsigned int*)(ws + (40ull << 20) + (128u << 10));   // 32 KB
    uint32_t*     tA      = (uint32_t*)   (ws + (40ull << 20) + (200u << 10));    // 4 KB
    uint32_t*     tB      = (uint32_t*)   (ws + (40ull << 20) + (208u << 10));    // 4 KB
    unsigned int* hist64  = (unsigned int*)(ws + (40ull << 20) + (216u << 10));   // 256 B
    unsigned int* cbase   = (unsigned int*)(ws + (40ull << 20) + (224u << 10));   // 260 B
    unsigned int* ccursor = (unsigned int*)(ws + (40ull << 20) + (232u << 10));   // 256 B
    double*       partials = (double*)    (ws + (40ull << 20) + (256u << 10));    // 48 KB (8-aligned)

    float* outf = (float*)d_out;
    uint32_t* outpolys = (uint32_t*)outf + 24;                      // 8*N, final floats
    uint32_t* barr1 = (uint32_t*)outf + 1024;                       // 16 MB scratch (pre-NTT)
    uint32_t* barr2 = (uint32_t*)outf + 1024 + (5u << 20);          // 16 MB scratch (pre-NTT)

    hipMemsetAsync(hist, 0, NBUCK * sizeof(unsigned int), stream);
    hipMemsetAsync(hist64, 0, 64 * sizeof(unsigned int), stream);

    twiddle_ab_kernel<<<4, 256, 0, stream>>>(tA, tB);
    twiddle_fill_kernel<<<NN / 256, 256, 0, stream>>>(tA, tB, Wfull);

    compress_kernel<<<2048, 256, 0, stream>>>(wl, wr, wo, w4, t1, t2, t3, t4, q, zp,
                                              tcomp, fcomp, hist64);
    scan64_kernel<<<1, 64, 0, stream>>>(hist64, cbase, ccursor);
    pass1_kernel<<<1024, 256, 0, stream>>>(tcomp, fcomp, ccursor, barr1);
    fine_hist_kernel<<<dim3(16, 64), 256, 0, stream>>>(barr1, cbase, hist);
    scan_kernel<<<1, 256, 0, stream>>>(hist, basearr, fcursor);
    pass2_kernel<<<dim3(16, 64), 256, 0, stream>>>(barr1, cbase, fcursor, barr2);
    bucket_sort_kernel<<<NBUCK, 256, 0, stream>>>(barr2, basearr, h1, h2);

    SrcPtrs sp;
    sp.p[0] = (const uint32_t*)wl;
    sp.p[1] = (const uint32_t*)wr;
    sp.p[2] = (const uint32_t*)wo;
    sp.p[3] = (const uint32_t*)w4;
    sp.p[4] = tcomp;
    sp.p[5] = fcomp;
    sp.p[6] = h1;
    sp.p[7] = h2;
    bitrev_kernel<<<dim3(512, 8), 256, 0, stream>>>(sp, outpolys);
    ntt_phase1_kernel<<<dim3(512, 8), 256, 0, stream>>>(outpolys, Wfull);
    ntt_phase2_kernel<<<2048, 256, 0, stream>>>(outpolys, Wfull, g, partials);

    reduce_commits_kernel<<<1, 256, 0, stream>>>(partials, outf);
}

// Round 9
// 357.047 us; speedup vs baseline: 3.8703x; 1.0631x over previous
//
#include <hip/hip_runtime.h>
#include <stdint.h>

#define PRIME 2013265921u
#define LOGN 21
#define NN (1u << LOGN)   // 2097152

// ---------- compile-time modular helpers ----------
constexpr uint32_t cpow(uint64_t b, uint64_t e) {
    uint64_t r = 1;
    b %= PRIME;
    while (e) {
        if (e & 1ull) r = r * b % PRIME;
        b = b * b % PRIME;
        e >>= 1;
    }
    return (uint32_t)r;
}
constexpr uint32_t cpinv() {           // PRIME^{-1} mod 2^32 (Newton)
    uint32_t inv = 1;
    for (int i = 0; i < 6; i++) inv *= 2u - PRIME * inv;
    return inv;
}
constexpr uint32_t NPRIME   = (uint32_t)(0u - cpinv());            // -P^{-1} mod 2^32
constexpr uint32_t RMODP    = (uint32_t)((1ull << 32) % PRIME);    // Mont(1)
constexpr uint32_t ROOT     = cpow(31u, (PRIME - 1) / NN);
constexpr uint32_t IROOT    = cpow(ROOT, PRIME - 2);
constexpr uint32_t IROOT1K  = cpow(IROOT, 1024);
constexpr uint32_t NINV     = cpow(NN, PRIME - 2);
constexpr uint32_t NINV_M   = (uint32_t)((((uint64_t)NINV) << 32) % PRIME);  // Mont(N^-1)
// J = iroot^(2^19): radix-4 second-stage twiddle offset constant, W[j+h] = W[j]*J
constexpr uint32_t JV       = cpow(IROOT, 1u << 19);
constexpr uint32_t JM       = (uint32_t)((((uint64_t)JV) << 32) % PRIME);    // Mont(J)

// ---------- modular arithmetic ----------
__device__ __forceinline__ uint32_t addmod(uint32_t a, uint32_t b) {
    uint32_t s = a + b; return (s >= PRIME) ? s - PRIME : s;
}
__device__ __forceinline__ uint32_t submod(uint32_t a, uint32_t b) {
    return (a >= b) ? (a - b) : (a + PRIME - b);
}
__device__ __forceinline__ uint32_t mulmod(uint32_t a, uint32_t b) {
    return (uint32_t)(((uint64_t)a * (uint64_t)b) % PRIME);
}
// Montgomery: montmul(a_normal, Mont(b)) = a*b mod P; montmul(Mont(a),Mont(b)) = Mont(ab)
__device__ __forceinline__ uint32_t montmul(uint32_t a, uint32_t b) {
    uint64_t t = (uint64_t)a * b;
    uint32_t m = (uint32_t)t * NPRIME;
    uint32_t u = (uint32_t)((t + (uint64_t)m * PRIME) >> 32);
    return (u >= PRIME) ? u - PRIME : u;
}
__device__ uint32_t powmod(uint32_t b, uint32_t e) {
    uint32_t r = 1u;
    while (e) {
        if (e & 1u) r = mulmod(r, b);
        b = mulmod(b, b);
        e >>= 1;
    }
    return r;
}
__device__ __forceinline__ uint32_t tomont(uint32_t x) {
    return (uint32_t)((((uint64_t)x) << 32) % PRIME);
}

// ---------- twiddles: A[i]=Mont(iroot^(1024 i)), B[i]=Mont(iroot^i), i<1024 ----------
__global__ void twiddle_ab_kernel(uint32_t* __restrict__ A, uint32_t* __restrict__ B) {
    uint32_t i = blockIdx.x * blockDim.x + threadIdx.x;   // < 1024
    B[i] = tomont(powmod(IROOT, i));
    A[i] = tomont(powmod(IROOT1K, i));
}
// Stage-packed table: Wfull[2^s + j] = Mont(iroot^(j << (20 - s))), j < 2^s, s=0..20
__global__ void twiddle_fill_kernel(const uint32_t* __restrict__ A, const uint32_t* __restrict__ B,
                                    uint32_t* __restrict__ Wfull) {
    uint32_t idx = blockIdx.x * blockDim.x + threadIdx.x;   // < 2^21
    if (idx == 0) { Wfull[0] = RMODP; return; }
    uint32_t s = 31u - __clz(idx);
    uint32_t j = idx ^ (1u << s);
    uint32_t e = j << (20u - s);                 // < 2^20
    Wfull[idx] = montmul(A[e >> 10], B[e & 1023u]);
}

// ---------- compress + fused coarse (64-bucket) histogram ----------
__global__ __launch_bounds__(256) void compress_kernel(
        const int* __restrict__ wl, const int* __restrict__ wr,
        const int* __restrict__ wo, const int* __restrict__ w4,
        const int* __restrict__ t1, const int* __restrict__ t2,
        const int* __restrict__ t3, const int* __restrict__ t4,
        const int* __restrict__ q,  const int* __restrict__ zp,
        uint32_t* __restrict__ tcomp, uint32_t* __restrict__ fcomp,
        unsigned int* __restrict__ hist64) {
    __shared__ unsigned int h64[64];
    if (threadIdx.x < 64) h64[threadIdx.x] = 0;
    __syncthreads();
    uint32_t z1 = ((uint32_t)zp[0]) % PRIME;
    uint32_t z2 = mulmod(z1, z1);
    uint32_t z3 = mulmod(z2, z1);
    for (uint32_t i = blockIdx.x * blockDim.x + threadIdx.x; i < NN; i += gridDim.x * blockDim.x) {
        uint32_t t = addmod(addmod((uint32_t)t1[i], mulmod((uint32_t)t2[i], z1)),
                            addmod(mulmod((uint32_t)t3[i], z2), mulmod((uint32_t)t4[i], z3)));
        uint32_t w = addmod(addmod((uint32_t)wl[i], mulmod((uint32_t)wr[i], z1)),
                            addmod(mulmod((uint32_t)wo[i], z2), mulmod((uint32_t)w4[i], z3)));
        uint32_t f = (q[i] != 0) ? w : t;
        tcomp[i] = t;
        fcomp[i] = f;
        atomicAdd(&h64[t >> 25], 1u);
        atomicAdd(&h64[f >> 25], 1u);
    }
    __syncthreads();
    if (threadIdx.x < 64 && h64[threadIdx.x])
        atomicAdd(&hist64[threadIdx.x], h64[threadIdx.x]);
}

// ---------- sort ----------
#define NBUCK 8192

__global__ void scan64_kernel(const unsigned int* __restrict__ hist64,
                              unsigned int* __restrict__ cbase, unsigned int* __restrict__ ccursor) {
    if (threadIdx.x == 0) {
        unsigned int run = 0;
        for (int b = 0; b < 64; b++) { cbase[b] = run; ccursor[b] = run; run += hist64[b]; }
        cbase[64] = run;
    }
}

// pass 1: scatter into 64 coarse buckets with LDS grouping (coalesced run writes)
__global__ __launch_bounds__(256) void pass1_kernel(const uint32_t* __restrict__ tcomp,
                                                    const uint32_t* __restrict__ fcomp,
                                                    unsigned int* __restrict__ ccursor,
                                                    uint32_t* __restrict__ barr1) {
    __shared__ uint32_t grp[4096];
    __shared__ unsigned char grpb[4096];
    __shared__ unsigned int cnt[64], pref[64], curs[64], rbase[64];
    uint32_t base = blockIdx.x * 4096;    // grid 1024 covers 2NN exactly
    uint32_t tid = threadIdx.x;
    if (tid < 64) cnt[tid] = 0;
    __syncthreads();
    for (uint32_t l = tid; l < 4096; l += 256) {
        uint32_t gi = base + l;
        uint32_t v = (gi < NN) ? tcomp[gi] : fcomp[gi - NN];
        atomicAdd(&cnt[v >> 25], 1u);
    }
    __syncthreads();
    if (tid == 0) {
        unsigned int run = 0;
        for (int b = 0; b < 64; b++) { pref[b] = run; curs[b] = run; run += cnt[b]; }
    }
    __syncthreads();
    if (tid < 64 && cnt[tid]) rbase[tid] = atomicAdd(&ccursor[tid], cnt[tid]);
    for (uint32_t l = tid; l < 4096; l += 256) {
        uint32_t gi = base + l;
        uint32_t v = (gi < NN) ? tcomp[gi] : fcomp[gi - NN];
        uint32_t b = v >> 25;
        unsigned int p = atomicAdd(&curs[b], 1u);
        grp[p] = v; grpb[p] = (unsigned char)b;
    }
    __syncthreads();
    for (uint32_t l = tid; l < 4096; l += 256) {
        uint32_t b = grpb[l];
        barr1[rbase[b] + (l - pref[b])] = grp[l];
    }
}

// fine (8192-bucket) histogram from coarse-partitioned data
__global__ __launch_bounds__(256) void fine_hist_kernel(const uint32_t* __restrict__ barr1,
                                                        const unsigned int* __restrict__ cbase,
                                                        unsigned int* __restrict__ hist) {
    __shared__ unsigned int cnt[128];
    uint32_t tid = threadIdx.x;
    uint32_t reg = blockIdx.y;
    if (tid < 128) cnt[tid] = 0;
    __syncthreads();
    uint32_t lo = cbase[reg], hi = cbase[reg + 1];
    for (uint32_t i = lo + blockIdx.x * 256 + tid; i < hi; i += gridDim.x * 256)
        atomicAdd(&cnt[(barr1[i] >> 18) & 127u], 1u);
    __syncthreads();
    if (tid < 128 && cnt[tid]) atomicAdd(&hist[reg * 128 + tid], cnt[tid]);
}

__global__ void scan_kernel(const unsigned int* __restrict__ hist,
                            unsigned int* __restrict__ basearr, unsigned int* __restrict__ fcursor) {
    __shared__ unsigned int ls[256];
    int t = threadIdx.x;
    unsigned int local[32];
    unsigned int s = 0;
    for (int k = 0; k < 32; k++) { local[k] = hist[t * 32 + k]; s += local[k]; }
    ls[t] = s;
    __syncthreads();
    for (int off = 1; off < 256; off <<= 1) {
        unsigned int v = (t >= off) ? ls[t - off] : 0u;
        __syncthreads();
        ls[t] += v;
        __syncthreads();
    }
    unsigned int run = ls[t] - s;  // exclusive prefix
    for (int k = 0; k < 32; k++) {
        basearr[t * 32 + k] = run;
        fcursor[t * 32 + k] = run;
        run += local[k];
    }
    if (t == 255) basearr[NBUCK] = run;
}

// pass 2: within each coarse region, scatter into 128 fine buckets (LDS grouping)
__global__ __launch_bounds__(256) void pass2_kernel(const uint32_t* __restrict__ barr1,
                                                    const unsigned int* __restrict__ cbase,
                                                    unsigned int* __restrict__ fcursor,
                                                    uint32_t* __restrict__ barr2) {
    __shared__ uint32_t grp[4096];
    __shared__ unsigned char grpb[4096];
    __shared__ unsigned int cnt[128], pref[128], curs[128], rbase[128];
    uint32_t tid = threadIdx.x;
    uint32_t reg = blockIdx.y;
    uint32_t lo = cbase[reg], hi = cbase[reg + 1];
    for (uint32_t start = lo + blockIdx.x * 4096; start < hi; start += gridDim.x * 4096) {
        uint32_t n = min(4096u, hi - start);
        if (tid < 128) cnt[tid] = 0;
        __syncthreads();
        for (uint32_t l = tid; l < n; l += 256)
            atomicAdd(&cnt[(barr1[start + l] >> 18) & 127u], 1u);
        __syncthreads();
        if (tid == 0) {
            unsigned int run = 0;
            for (int b = 0; b < 128; b++) { pref[b] = run; curs[b] = run; run += cnt[b]; }
        }
        __syncthreads();
        if (tid < 128 && cnt[tid]) rbase[tid] = atomicAdd(&fcursor[reg * 128 + tid], cnt[tid]);
        for (uint32_t l = tid; l < n; l += 256) {
            uint32_t v = barr1[start + l];
            uint32_t b = (v >> 18) & 127u;
            unsigned int p = atomicAdd(&curs[b], 1u);
            grp[p] = v; grpb[p] = (unsigned char)b;
        }
        __syncthreads();
        for (uint32_t l = tid; l < n; l += 256) {
            uint32_t b = grpb[l];
            barr2[rbase[b] + (l - pref[b])] = grp[l];
        }
        __syncthreads();
    }
}

// ---------- per-bucket O(n) MSD counting sort ----------
__global__ __launch_bounds__(256) void bucket_sort_kernel(const uint32_t* __restrict__ barr,
                                                          const unsigned int* __restrict__ basearr,
                                                          uint32_t* __restrict__ h1, uint32_t* __restrict__ h2) {
    __shared__ uint32_t ord[4096];
    __shared__ unsigned int cnt[128], pref[128], curs[128];
    uint32_t b  = blockIdx.x;
    uint32_t lo = basearr[b], hi = basearr[b + 1];
    uint32_t n  = hi - lo;
    if (n == 0) return;
    if (n > 4096) n = 4096;   // unreachable for this distribution
    uint32_t tid = threadIdx.x;
    if (tid < 128) cnt[tid] = 0;
    __syncthreads();
    for (uint32_t i = tid; i < n; i += 256)
        atomicAdd(&cnt[(barr[lo + i] >> 11) & 127u], 1u);
    __syncthreads();
    if (tid == 0) {
        unsigned int run = 0;
        for (int d = 0; d < 128; d++) { pref[d] = run; curs[d] = run; run += cnt[d]; }
    }
    __syncthreads();
    for (uint32_t i = tid; i < n; i += 256) {
        uint32_t v = barr[lo + i];
        uint32_t d = (v >> 11) & 127u;
        unsigned int p = atomicAdd(&curs[d], 1u);
        ord[p] = v;
    }
    __syncthreads();
    for (uint32_t p = tid; p < n; p += 256) {
        uint32_t v = ord[p];
        uint32_t d = (v >> 11) & 127u;
        uint32_t l0 = pref[d], l1 = l0 + cnt[d];
        uint32_t r = 0;
        for (uint32_t q = l0; q < l1; q++) {
            uint32_t u = ord[q];
            r += (u < v) || (u == v && q < p);
        }
        uint32_t gp = lo + l0 + r;
        if (gp & 1) h2[gp >> 1] = v; else h1[gp >> 1] = v;
    }
}

// ---------- bit-reversal permute: dst[i] = src[rev21(i)], tiled ----------
struct SrcPtrs { const uint32_t* p[8]; };

__global__ void bitrev_kernel(SrcPtrs srcs, uint32_t* __restrict__ dst) {
    __shared__ uint32_t tile[64 * 65];
    uint32_t poly = blockIdx.y;
    const uint32_t* src = srcs.p[poly];
    uint32_t* out = dst + (size_t)poly * NN;
    uint32_t m  = blockIdx.x;                 // 9-bit middle
    uint32_t rm = __brev(m) >> 23;            // rev9
    for (uint32_t l = threadIdx.x; l < 4096; l += blockDim.x) {
        uint32_t u = l >> 6, v = l & 63;
        tile[u * 65 + v] = src[(u << 15) | (rm << 6) | v];
    }
    __syncthreads();
    for (uint32_t l = threadIdx.x; l < 4096; l += blockDim.x) {
        uint32_t a = l >> 6, b = l & 63;
        uint32_t ra = __brev(a) >> 26, rb = __brev(b) >> 26;  // rev6
        out[(a << 15) | (m << 6) | b] = tile[rb * 65 + ra];
    }
}

// ---------- NTT stages 1..12, radix-4 (6 rounds); twiddles in LDS; n_inv folded ----------
__device__ __forceinline__ uint32_t padi(uint32_t i) { return i + (i >> 5); }

__global__ __launch_bounds__(256) void ntt_phase1_kernel(uint32_t* __restrict__ polys,
                                                         const uint32_t* __restrict__ Wfull) {
    __shared__ uint32_t wt[4096];
    __shared__ uint32_t sd[4224];     // padded: i + (i>>5)
    uint32_t* x = polys + (size_t)blockIdx.y * NN + (size_t)blockIdx.x * 4096;
    for (uint32_t l = threadIdx.x; l < 4096; l += 256) {
        wt[l] = Wfull[l];
        sd[padi(l)] = x[l];
    }
    __syncthreads();
    // 6 radix-4 rounds = stage pairs (1,2),(3,4),...,(11,12)
    #pragma unroll
    for (int t = 0; t < 6; t++) {
        uint32_t h = 1u << (2 * t);
        #pragma unroll
        for (uint32_t m = 0; m < 4; m++) {
            uint32_t q = threadIdx.x + (m << 8);     // unit 0..1023
            uint32_t j = q & (h - 1);
            uint32_t grp = q >> (2 * t);
            uint32_t i0 = (grp << (2 * t + 2)) + j;
            uint32_t w1 = wt[h + j];
            uint32_t w2 = wt[2 * h + j];
            uint32_t w2j = montmul(w2, JM);
            uint32_t p0 = padi(i0), p1 = padi(i0 + h), p2 = padi(i0 + 2 * h), p3 = padi(i0 + 3 * h);
            uint32_t a0 = sd[p0], a1 = sd[p1], a2 = sd[p2], a3 = sd[p3];
            uint32_t t1 = montmul(w1, a1), t3 = montmul(w1, a3);
            uint32_t b0 = addmod(a0, t1), b1 = submod(a0, t1);
            uint32_t b2 = addmod(a2, t3), b3 = submod(a2, t3);
            uint32_t u2 = montmul(w2, b2), u3 = montmul(w2j, b3);
            sd[p0] = addmod(b0, u2);
            sd[p2] = submod(b0, u2);
            sd[p1] = addmod(b1, u3);
            sd[p3] = submod(b1, u3);
        }
        __syncthreads();
    }
    // fold in N^-1 scaling (linear, commutes with remaining stages)
    for (uint32_t l = threadIdx.x; l < 4096; l += 256)
        x[l] = montmul(sd[padi(l)], NINV_M);
}

// ---------- NTT stages 13..21, radix-4 x4 + radix-2; fused commit; XCD remap ----------
__device__ __forceinline__ uint32_t pad16(uint32_t idx) { return idx + (idx >> 5); }

__global__ __launch_bounds__(256) void ntt_phase2_kernel(uint32_t* __restrict__ polys,
                                                         const uint32_t* __restrict__ Wfull,
                                                         const float* __restrict__ g,
                                                         double* __restrict__ partials) {
    __shared__ uint32_t sd[8448];     // 8192 data + pad
    __shared__ uint32_t rowt[512];    // rowt[hb+kk] = Mont(iroot^(kk·4096 << (8-s)))
    __shared__ double red[256];
    // XCD-aware remap: group the 8 polys of one c0-slice consecutively on one XCD
    uint32_t b = blockIdx.x;              // 0..2047
    uint32_t xcd = b & 7u, k = b >> 3;    // k: 0..255
    uint32_t c0_idx = xcd * 32u + (k >> 3);
    uint32_t poly = k & 7u;
    uint32_t* x = polys + (size_t)poly * NN;
    uint32_t c0 = c0_idx * 16u;
    uint32_t tid = threadIdx.x;
    uint32_t c = tid & 15u;
    uint32_t rt = tid >> 4;           // 0..15

    for (uint32_t l = tid; l < 8192; l += 256) {
        uint32_t bb = l >> 4, cc = l & 15;
        sd[pad16(l)] = x[c0 + cc + (bb << 12)];
    }
    rowt[tid]       = (tid == 0) ? RMODP : Wfull[tid << 12];
    rowt[tid + 256] = Wfull[(uint32_t)(tid + 256) << 12];
    uint32_t cw[9];
    #pragma unroll
    for (int s = 0; s < 9; s++) cw[s] = Wfull[(1u << (12 + s)) + c0 + c];
    __syncthreads();

    // 4 radix-4 rounds: local stage pairs (0,1),(2,3),(4,5),(6,7)
    #pragma unroll
    for (int s = 0; s < 8; s += 2) {
        uint32_t h = 1u << s;
        #pragma unroll
        for (uint32_t m = 0; m < 8; m++) {
            uint32_t p = (rt << 3) + m;          // radix-4 unit 0..127
            uint32_t kk = p & (h - 1);
            uint32_t grp = p >> s;
            uint32_t r0 = (grp << (s + 2)) + kk;
            uint32_t w1  = montmul(rowt[h + kk], cw[s]);
            uint32_t w2  = montmul(rowt[2 * h + kk], cw[s + 1]);
            uint32_t w2j = montmul(w2, JM);
            uint32_t i0 = pad16((r0 << 4) + c);
            uint32_t i1 = pad16(((r0 + h) << 4) + c);
            uint32_t i2 = pad16(((r0 + 2 * h) << 4) + c);
            uint32_t i3 = pad16(((r0 + 3 * h) << 4) + c);
            uint32_t a0 = sd[i0], a1 = sd[i1], a2 = sd[i2], a3 = sd[i3];
            uint32_t t1 = montmul(w1, a1), t3 = montmul(w1, a3);
            uint32_t b0 = addmod(a0, t1), b1 = submod(a0, t1);
            uint32_t b2 = addmod(a2, t3), b3 = submod(a2, t3);
            uint32_t u2 = montmul(w2, b2), u3 = montmul(w2j, b3);
            sd[i0] = addmod(b0, u2);
            sd[i2] = submod(b0, u2);
            sd[i1] = addmod(b1, u3);
            sd[i3] = submod(b1, u3);
        }
        __syncthreads();
    }
    // final radix-2 stage (local s=8, hb=256)
    #pragma unroll
    for (uint32_t m = 0; m < 16; m++) {
        uint32_t kk = (rt << 4) + m;       // 0..255
        uint32_t w = montmul(rowt[256 + kk], cw[8]);
        uint32_t i0 = pad16((kk << 4) + c), i1 = pad16(((kk + 256) << 4) + c);
        uint32_t u = sd[i0];
        uint32_t v = montmul(sd[i1], w);
        sd[i0] = addmod(u, v);
        sd[i1] = submod(u, v);
    }
    __syncthreads();

    // epilogue: final float values (regular stores) + fused commit partials
    float* xf = (float*)x;
    const float invp = (float)(1.0 / 2013265921.0);
    double a0 = 0.0, a1 = 0.0, a2 = 0.0;
    for (uint32_t l = tid; l < 8192; l += 256) {
        uint32_t bb = l >> 4, cc = l & 15;
        uint32_t idx = c0 + cc + (bb << 12);
        float fv = (float)sd[pad16(l)];
        xf[idx] = fv;
        float s = fv * invp;
        a0 += (double)(s * g[idx * 3 + 0]);
        a1 += (double)(s * g[idx * 3 + 1]);
        a2 += (double)(s * g[idx * 3 + 2]);
    }
    double v3[3] = {a0, a1, a2};
    #pragma unroll
    for (int kq = 0; kq < 3; kq++) {
        __syncthreads();
        red[tid] = v3[kq];
        __syncthreads();
        for (int off = 128; off > 0; off >>= 1) {
            if (tid < off) red[tid] += red[tid + off];
            __syncthreads();
        }
        if (tid == 0) partials[((size_t)poly * 256 + c0_idx) * 3 + kq] = red[0];
    }
}

// ---------- final commit reduce: 8 polys x 256 blocks x 3 comps -> 24 floats ----------
__global__ void reduce_commits_kernel(const double* __restrict__ partials, float* __restrict__ outf) {
    __shared__ double red[256];
    int t = threadIdx.x;
    for (int k = 0; k < 24; k++) {
        int p = k / 3, cc = k % 3;
        red[t] = partials[((size_t)p * 256 + t) * 3 + cc];
        __syncthreads();
        for (int off = 128; off > 0; off >>= 1) {
            if (t < off) red[t] += red[t + off];
            __syncthreads();
        }
        if (t == 0) outf[k] = (float)red[0];
        __syncthreads();
    }
}

extern "C" void kernel_launch(void* const* d_in, const int* in_sizes, int n_in,
                              void* d_out, int out_size, void* d_ws, size_t ws_size,
                              hipStream_t stream) {
    const int* wl = (const int*)d_in[0];
    const int* wr = (const int*)d_in[1];
    const int* wo = (const int*)d_in[2];
    const int* w4 = (const int*)d_in[3];
    const int* t1 = (const int*)d_in[4];
    const int* t2 = (const int*)d_in[5];
    const int* t3 = (const int*)d_in[6];
    const int* t4 = (const int*)d_in[7];
    const int* q  = (const int*)d_in[8];
    const float* g = (const float*)d_in[9];
    const int* zp = (const int*)d_in[10];

    char* ws = (char*)d_ws;
    uint32_t* Wfull  = (uint32_t*)(ws);                       // 8 MB
    uint32_t* tcomp  = (uint32_t*)(ws + (8ull  << 20));       // 8 MB
    uint32_t* fcomp  = (uint32_t*)(ws + (16ull << 20));       // 8 MB
    uint32_t* h1     = (uint32_t*)(ws + (24ull << 20));       // 8 MB
    uint32_t* h2     = (uint32_t*)(ws + (32ull << 20));       // 8 MB
    // small buffers at 64 KiB-aligned offsets
    unsigned int* hist    = (unsigned int*)(ws + (40ull << 20));                  // 32 KB
    unsigned int* basearr = (unsigned int*)(ws + (40ull << 20) + (64u  << 10));   // 32 KB+4
    unsigned int* fcursor = (unsigned int*)(ws + (40ull << 20) + (128u << 10));   // 32 KB
    uint32_t*     tA      = (uint32_t*)   (ws + (40ull << 20) + (200u << 10));    // 4 KB
    uint32_t*     tB      = (uint32_t*)   (ws + (40ull << 20) + (208u << 10));    // 4 KB
    unsigned int* hist64  = (unsigned int*)(ws + (40ull << 20) + (216u << 10));   // 256 B
    unsigned int* cbase   = (unsigned int*)(ws + (40ull << 20) + (224u << 10));   // 260 B
    unsigned int* ccursor = (unsigned int*)(ws + (40ull << 20) + (232u << 10));   // 256 B
    double*       partials = (double*)    (ws + (40ull << 20) + (256u << 10));    // 48 KB (8-aligned)

    float* outf = (float*)d_out;
    uint32_t* outpolys = (uint32_t*)outf + 24;                      // 8*N, final floats
    uint32_t* barr1 = (uint32_t*)outf + 1024;                       // 16 MB scratch (pre-NTT)
    uint32_t* barr2 = (uint32_t*)outf + 1024 + (5u << 20);          // 16 MB scratch (pre-NTT)

    hipMemsetAsync(hist, 0, NBUCK * sizeof(unsigned int), stream);
    hipMemsetAsync(hist64, 0, 64 * sizeof(unsigned int), stream);

    twiddle_ab_kernel<<<4, 256, 0, stream>>>(tA, tB);
    twiddle_fill_kernel<<<NN / 256, 256, 0, stream>>>(tA, tB, Wfull);

    compress_kernel<<<2048, 256, 0, stream>>>(wl, wr, wo, w4, t1, t2, t3, t4, q, zp,
                                              tcomp, fcomp, hist64);
    scan64_kernel<<<1, 64, 0, stream>>>(hist64, cbase, ccursor);
    pass1_kernel<<<1024, 256, 0, stream>>>(tcomp, fcomp, ccursor, barr1);
    fine_hist_kernel<<<dim3(16, 64), 256, 0, stream>>>(barr1, cbase, hist);
    scan_kernel<<<1, 256, 0, stream>>>(hist, basearr, fcursor);
    pass2_kernel<<<dim3(16, 64), 256, 0, stream>>>(barr1, cbase, fcursor, barr2);
    bucket_sort_kernel<<<NBUCK, 256, 0, stream>>>(barr2, basearr, h1, h2);

    SrcPtrs sp;
    sp.p[0] = (const uint32_t*)wl;
    sp.p[1] = (const uint32_t*)wr;
    sp.p[2] = (const uint32_t*)wo;
    sp.p[3] = (const uint32_t*)w4;
    sp.p[4] = tcomp;
    sp.p[5] = fcomp;
    sp.p[6] = h1;
    sp.p[7] = h2;
    bitrev_kernel<<<dim3(512, 8), 256, 0, stream>>>(sp, outpolys);
    ntt_phase1_kernel<<<dim3(512, 8), 256, 0, stream>>>(outpolys, Wfull);
    ntt_phase2_kernel<<<2048, 256, 0, stream>>>(outpolys, Wfull, g, partials);

    reduce_commits_kernel<<<1, 256, 0, stream>>>(partials, outf);
}

// Round 10
// 346.404 us; speedup vs baseline: 3.9893x; 1.0307x over previous
//
#include <hip/hip_runtime.h>
#include <stdint.h>

#define PRIME 2013265921u
#define LOGN 21
#define NN (1u << LOGN)   // 2097152

// ---------- compile-time modular helpers ----------
constexpr uint32_t cpow(uint64_t b, uint64_t e) {
    uint64_t r = 1;
    b %= PRIME;
    while (e) {
        if (e & 1ull) r = r * b % PRIME;
        b = b * b % PRIME;
        e >>= 1;
    }
    return (uint32_t)r;
}
constexpr uint32_t cpinv() {           // PRIME^{-1} mod 2^32 (Newton)
    uint32_t inv = 1;
    for (int i = 0; i < 6; i++) inv *= 2u - PRIME * inv;
    return inv;
}
constexpr uint32_t NPRIME   = (uint32_t)(0u - cpinv());            // -P^{-1} mod 2^32
constexpr uint32_t RMODP    = (uint32_t)((1ull << 32) % PRIME);    // Mont(1)
constexpr uint32_t ROOT     = cpow(31u, (PRIME - 1) / NN);
constexpr uint32_t IROOT    = cpow(ROOT, PRIME - 2);
constexpr uint32_t IROOT1K  = cpow(IROOT, 1024);
constexpr uint32_t NINV     = cpow(NN, PRIME - 2);
constexpr uint32_t NINV_M   = (uint32_t)((((uint64_t)NINV) << 32) % PRIME);  // Mont(N^-1)

// ---------- modular arithmetic ----------
__device__ __forceinline__ uint32_t addmod(uint32_t a, uint32_t b) {
    uint32_t s = a + b; return (s >= PRIME) ? s - PRIME : s;
}
__device__ __forceinline__ uint32_t submod(uint32_t a, uint32_t b) {
    return (a >= b) ? (a - b) : (a + PRIME - b);
}
__device__ __forceinline__ uint32_t mulmod(uint32_t a, uint32_t b) {
    return (uint32_t)(((uint64_t)a * (uint64_t)b) % PRIME);
}
// Montgomery: montmul(a_normal, Mont(b)) = a*b mod P; montmul(Mont(a),Mont(b)) = Mont(ab)
__device__ __forceinline__ uint32_t montmul(uint32_t a, uint32_t b) {
    uint64_t t = (uint64_t)a * b;
    uint32_t m = (uint32_t)t * NPRIME;
    uint32_t u = (uint32_t)((t + (uint64_t)m * PRIME) >> 32);
    return (u >= PRIME) ? u - PRIME : u;
}
__device__ uint32_t powmod(uint32_t b, uint32_t e) {
    uint32_t r = 1u;
    while (e) {
        if (e & 1u) r = mulmod(r, b);
        b = mulmod(b, b);
        e >>= 1;
    }
    return r;
}
__device__ __forceinline__ uint32_t tomont(uint32_t x) {
    return (uint32_t)((((uint64_t)x) << 32) % PRIME);
}

// ---------- twiddles: A[i]=Mont(iroot^(1024 i)), B[i]=Mont(iroot^i), i<1024 ----------
__global__ void twiddle_ab_kernel(uint32_t* __restrict__ A, uint32_t* __restrict__ B) {
    uint32_t i = blockIdx.x * blockDim.x + threadIdx.x;   // < 1024
    B[i] = tomont(powmod(IROOT, i));
    A[i] = tomont(powmod(IROOT1K, i));
}
// Stage-packed table: Wfull[2^s + j] = Mont(iroot^(j << (20 - s))), j < 2^s, s=0..20
__global__ void twiddle_fill_kernel(const uint32_t* __restrict__ A, const uint32_t* __restrict__ B,
                                    uint32_t* __restrict__ Wfull) {
    uint32_t idx = blockIdx.x * blockDim.x + threadIdx.x;   // < 2^21
    if (idx == 0) { Wfull[0] = RMODP; return; }
    uint32_t s = 31u - __clz(idx);
    uint32_t j = idx ^ (1u << s);
    uint32_t e = j << (20u - s);                 // < 2^20
    Wfull[idx] = montmul(A[e >> 10], B[e & 1023u]);
}

// ---------- compress + fused coarse (64-bucket) histogram ----------
__global__ __launch_bounds__(256) void compress_kernel(
        const int* __restrict__ wl, const int* __restrict__ wr,
        const int* __restrict__ wo, const int* __restrict__ w4,
        const int* __restrict__ t1, const int* __restrict__ t2,
        const int* __restrict__ t3, const int* __restrict__ t4,
        const int* __restrict__ q,  const int* __restrict__ zp,
        uint32_t* __restrict__ tcomp, uint32_t* __restrict__ fcomp,
        unsigned int* __restrict__ hist64) {
    __shared__ unsigned int h64[64];
    if (threadIdx.x < 64) h64[threadIdx.x] = 0;
    __syncthreads();
    uint32_t z1 = ((uint32_t)zp[0]) % PRIME;
    uint32_t z2 = mulmod(z1, z1);
    uint32_t z3 = mulmod(z2, z1);
    for (uint32_t i = blockIdx.x * blockDim.x + threadIdx.x; i < NN; i += gridDim.x * blockDim.x) {
        uint32_t t = addmod(addmod((uint32_t)t1[i], mulmod((uint32_t)t2[i], z1)),
                            addmod(mulmod((uint32_t)t3[i], z2), mulmod((uint32_t)t4[i], z3)));
        uint32_t w = addmod(addmod((uint32_t)wl[i], mulmod((uint32_t)wr[i], z1)),
                            addmod(mulmod((uint32_t)wo[i], z2), mulmod((uint32_t)w4[i], z3)));
        uint32_t f = (q[i] != 0) ? w : t;
        tcomp[i] = t;
        fcomp[i] = f;
        atomicAdd(&h64[t >> 25], 1u);
        atomicAdd(&h64[f >> 25], 1u);
    }
    __syncthreads();
    if (threadIdx.x < 64 && h64[threadIdx.x])
        atomicAdd(&hist64[threadIdx.x], h64[threadIdx.x]);
}

// ---------- sort ----------
#define NBUCK 8192

__global__ void scan64_kernel(const unsigned int* __restrict__ hist64,
                              unsigned int* __restrict__ cbase, unsigned int* __restrict__ ccursor) {
    if (threadIdx.x == 0) {
        unsigned int run = 0;
        for (int b = 0; b < 64; b++) { cbase[b] = run; ccursor[b] = run; run += hist64[b]; }
        cbase[64] = run;
    }
}

// pass 1: scatter into 64 coarse buckets with LDS grouping (coalesced run writes)
__global__ __launch_bounds__(256) void pass1_kernel(const uint32_t* __restrict__ tcomp,
                                                    const uint32_t* __restrict__ fcomp,
                                                    unsigned int* __restrict__ ccursor,
                                                    uint32_t* __restrict__ barr1) {
    __shared__ uint32_t grp[4096];
    __shared__ unsigned char grpb[4096];
    __shared__ unsigned int cnt[64], pref[64], curs[64], rbase[64];
    uint32_t base = blockIdx.x * 4096;    // grid 1024 covers 2NN exactly
    uint32_t tid = threadIdx.x;
    if (tid < 64) cnt[tid] = 0;
    __syncthreads();
    for (uint32_t l = tid; l < 4096; l += 256) {
        uint32_t gi = base + l;
        uint32_t v = (gi < NN) ? tcomp[gi] : fcomp[gi - NN];
        atomicAdd(&cnt[v >> 25], 1u);
    }
    __syncthreads();
    if (tid == 0) {
        unsigned int run = 0;
        for (int b = 0; b < 64; b++) { pref[b] = run; curs[b] = run; run += cnt[b]; }
    }
    __syncthreads();
    if (tid < 64 && cnt[tid]) rbase[tid] = atomicAdd(&ccursor[tid], cnt[tid]);
    for (uint32_t l = tid; l < 4096; l += 256) {
        uint32_t gi = base + l;
        uint32_t v = (gi < NN) ? tcomp[gi] : fcomp[gi - NN];
        uint32_t b = v >> 25;
        unsigned int p = atomicAdd(&curs[b], 1u);
        grp[p] = v; grpb[p] = (unsigned char)b;
    }
    __syncthreads();
    for (uint32_t l = tid; l < 4096; l += 256) {
        uint32_t b = grpb[l];
        barr1[rbase[b] + (l - pref[b])] = grp[l];
    }
}

// fine (8192-bucket) histogram from coarse-partitioned data
__global__ __launch_bounds__(256) void fine_hist_kernel(const uint32_t* __restrict__ barr1,
                                                        const unsigned int* __restrict__ cbase,
                                                        unsigned int* __restrict__ hist) {
    __shared__ unsigned int cnt[128];
    uint32_t tid = threadIdx.x;
    uint32_t reg = blockIdx.y;
    if (tid < 128) cnt[tid] = 0;
    __syncthreads();
    uint32_t lo = cbase[reg], hi = cbase[reg + 1];
    for (uint32_t i = lo + blockIdx.x * 256 + tid; i < hi; i += gridDim.x * 256)
        atomicAdd(&cnt[(barr1[i] >> 18) & 127u], 1u);
    __syncthreads();
    if (tid < 128 && cnt[tid]) atomicAdd(&hist[reg * 128 + tid], cnt[tid]);
}

__global__ void scan_kernel(const unsigned int* __restrict__ hist,
                            unsigned int* __restrict__ basearr, unsigned int* __restrict__ fcursor) {
    __shared__ unsigned int ls[256];
    int t = threadIdx.x;
    unsigned int local[32];
    unsigned int s = 0;
    for (int k = 0; k < 32; k++) { local[k] = hist[t * 32 + k]; s += local[k]; }
    ls[t] = s;
    __syncthreads();
    for (int off = 1; off < 256; off <<= 1) {
        unsigned int v = (t >= off) ? ls[t - off] : 0u;
        __syncthreads();
        ls[t] += v;
        __syncthreads();
    }
    unsigned int run = ls[t] - s;  // exclusive prefix
    for (int k = 0; k < 32; k++) {
        basearr[t * 32 + k] = run;
        fcursor[t * 32 + k] = run;
        run += local[k];
    }
    if (t == 255) basearr[NBUCK] = run;
}

// pass 2: within each coarse region, scatter into 128 fine buckets (LDS grouping)
__global__ __launch_bounds__(256) void pass2_kernel(const uint32_t* __restrict__ barr1,
                                                    const unsigned int* __restrict__ cbase,
                                                    unsigned int* __restrict__ fcursor,
                                                    uint32_t* __restrict__ barr2) {
    __shared__ uint32_t grp[4096];
    __shared__ unsigned char grpb[4096];
    __shared__ unsigned int cnt[128], pref[128], curs[128], rbase[128];
    uint32_t tid = threadIdx.x;
    uint32_t reg = blockIdx.y;
    uint32_t lo = cbase[reg], hi = cbase[reg + 1];
    for (uint32_t start = lo + blockIdx.x * 4096; start < hi; start += gridDim.x * 4096) {
        uint32_t n = min(4096u, hi - start);
        if (tid < 128) cnt[tid] = 0;
        __syncthreads();
        for (uint32_t l = tid; l < n; l += 256)
            atomicAdd(&cnt[(barr1[start + l] >> 18) & 127u], 1u);
        __syncthreads();
        if (tid == 0) {
            unsigned int run = 0;
            for (int b = 0; b < 128; b++) { pref[b] = run; curs[b] = run; run += cnt[b]; }
        }
        __syncthreads();
        if (tid < 128 && cnt[tid]) rbase[tid] = atomicAdd(&fcursor[reg * 128 + tid], cnt[tid]);
        for (uint32_t l = tid; l < n; l += 256) {
            uint32_t v = barr1[start + l];
            uint32_t b = (v >> 18) & 127u;
            unsigned int p = atomicAdd(&curs[b], 1u);
            grp[p] = v; grpb[p] = (unsigned char)b;
        }
        __syncthreads();
        for (uint32_t l = tid; l < n; l += 256) {
            uint32_t b = grpb[l];
            barr2[rbase[b] + (l - pref[b])] = grp[l];
        }
        __syncthreads();
    }
}

// ---------- per-bucket O(n) MSD counting sort ----------
__global__ __launch_bounds__(256) void bucket_sort_kernel(const uint32_t* __restrict__ barr,
                                                          const unsigned int* __restrict__ basearr,
                                                          uint32_t* __restrict__ h1, uint32_t* __restrict__ h2) {
    __shared__ uint32_t ord[4096];
    __shared__ unsigned int cnt[128], pref[128], curs[128];
    uint32_t b  = blockIdx.x;
    uint32_t lo = basearr[b], hi = basearr[b + 1];
    uint32_t n  = hi - lo;
    if (n == 0) return;
    if (n > 4096) n = 4096;   // unreachable for this distribution
    uint32_t tid = threadIdx.x;
    if (tid < 128) cnt[tid] = 0;
    __syncthreads();
    for (uint32_t i = tid; i < n; i += 256)
        atomicAdd(&cnt[(barr[lo + i] >> 11) & 127u], 1u);
    __syncthreads();
    if (tid == 0) {
        unsigned int run = 0;
        for (int d = 0; d < 128; d++) { pref[d] = run; curs[d] = run; run += cnt[d]; }
    }
    __syncthreads();
    for (uint32_t i = tid; i < n; i += 256) {
        uint32_t v = barr[lo + i];
        uint32_t d = (v >> 11) & 127u;
        unsigned int p = atomicAdd(&curs[d], 1u);
        ord[p] = v;
    }
    __syncthreads();
    for (uint32_t p = tid; p < n; p += 256) {
        uint32_t v = ord[p];
        uint32_t d = (v >> 11) & 127u;
        uint32_t l0 = pref[d], l1 = l0 + cnt[d];
        uint32_t r = 0;
        for (uint32_t q = l0; q < l1; q++) {
            uint32_t u = ord[q];
            r += (u < v) || (u == v && q < p);
        }
        uint32_t gp = lo + l0 + r;
        if (gp & 1) h2[gp >> 1] = v; else h1[gp >> 1] = v;
    }
}

// ---------- bit-reversal permute: dst[i] = src[rev21(i)], tiled ----------
struct SrcPtrs { const uint32_t* p[8]; };

__global__ void bitrev_kernel(SrcPtrs srcs, uint32_t* __restrict__ dst) {
    __shared__ uint32_t tile[64 * 65];
    uint32_t poly = blockIdx.y;
    const uint32_t* src = srcs.p[poly];
    uint32_t* out = dst + (size_t)poly * NN;
    uint32_t m  = blockIdx.x;                 // 9-bit middle
    uint32_t rm = __brev(m) >> 23;            // rev9
    for (uint32_t l = threadIdx.x; l < 4096; l += blockDim.x) {
        uint32_t u = l >> 6, v = l & 63;
        tile[u * 65 + v] = src[(u << 15) | (rm << 6) | v];
    }
    __syncthreads();
    for (uint32_t l = threadIdx.x; l < 4096; l += blockDim.x) {
        uint32_t a = l >> 6, b = l & 63;
        uint32_t ra = __brev(a) >> 26, rb = __brev(b) >> 26;  // rev6
        out[(a << 15) | (m << 6) | b] = tile[rb * 65 + ra];
    }
}

// ---------- NTT stages 1..12, radix-4 (6 rounds); twiddles in LDS; n_inv folded ----------
// w2j trick: W_{s+1}[j]*J = W_{s+1}[j+h]  (J = iroot^(2^19)) -> wt[3h+j], no montmul.
__device__ __forceinline__ uint32_t padi(uint32_t i) { return i + (i >> 5); }

__global__ __launch_bounds__(256) void ntt_phase1_kernel(uint32_t* __restrict__ polys,
                                                         const uint32_t* __restrict__ Wfull) {
    __shared__ uint32_t wt[4096];
    __shared__ uint32_t sd[4224];     // padded: i + (i>>5)
    uint32_t* x = polys + (size_t)blockIdx.y * NN + (size_t)blockIdx.x * 4096;
    for (uint32_t l = threadIdx.x; l < 4096; l += 256) {
        wt[l] = Wfull[l];
        sd[padi(l)] = x[l];
    }
    __syncthreads();
    // 6 radix-4 rounds = stage pairs (1,2),(3,4),...,(11,12)
    #pragma unroll
    for (int t = 0; t < 6; t++) {
        uint32_t h = 1u << (2 * t);
        #pragma unroll
        for (uint32_t m = 0; m < 4; m++) {
            uint32_t q = threadIdx.x + (m << 8);     // unit 0..1023
            uint32_t j = q & (h - 1);
            uint32_t grp = q >> (2 * t);
            uint32_t i0 = (grp << (2 * t + 2)) + j;
            uint32_t w1  = wt[h + j];
            uint32_t w2  = wt[2 * h + j];
            uint32_t w2j = wt[3 * h + j];
            uint32_t p0 = padi(i0), p1 = padi(i0 + h), p2 = padi(i0 + 2 * h), p3 = padi(i0 + 3 * h);
            uint32_t a0 = sd[p0], a1 = sd[p1], a2 = sd[p2], a3 = sd[p3];
            uint32_t t1 = montmul(w1, a1), t3 = montmul(w1, a3);
            uint32_t b0 = addmod(a0, t1), b1 = submod(a0, t1);
            uint32_t b2 = addmod(a2, t3), b3 = submod(a2, t3);
            uint32_t u2 = montmul(w2, b2), u3 = montmul(w2j, b3);
            sd[p0] = addmod(b0, u2);
            sd[p2] = submod(b0, u2);
            sd[p1] = addmod(b1, u3);
            sd[p3] = submod(b1, u3);
        }
        __syncthreads();
    }
    // fold in N^-1 scaling (linear, commutes with remaining stages)
    for (uint32_t l = threadIdx.x; l < 4096; l += 256)
        x[l] = montmul(sd[padi(l)], NINV_M);
}

// ---------- NTT stages 13..21, radix-4 x4 + radix-2; fused commit; XCD remap ----------
__device__ __forceinline__ uint32_t pad16(uint32_t idx) { return idx + (idx >> 5); }

__global__ __launch_bounds__(256) void ntt_phase2_kernel(uint32_t* __restrict__ polys,
                                                         const uint32_t* __restrict__ Wfull,
                                                         const float* __restrict__ g,
                                                         double* __restrict__ partials) {
    __shared__ uint32_t sd[8448];     // 8192 data + pad
    __shared__ uint32_t rowt[512];    // rowt[hb+kk] = Mont(iroot^(kk·4096 << (8-s)))
    __shared__ double red[256];
    // XCD-aware remap, poly-major within XCD: concurrent blocks on one XCD process
    // ADJACENT c0 slices of the SAME poly -> 64B segments merge into DRAM row hits.
    uint32_t b = blockIdx.x;              // 0..2047
    uint32_t xcd = b & 7u, k = b >> 3;    // k: 0..255
    uint32_t poly = k >> 5;               // 0..7
    uint32_t c0_idx = xcd * 32u + (k & 31u);
    uint32_t* x = polys + (size_t)poly * NN;
    uint32_t c0 = c0_idx * 16u;
    uint32_t tid = threadIdx.x;
    uint32_t c = tid & 15u;
    uint32_t rt = tid >> 4;           // 0..15

    for (uint32_t l = tid; l < 8192; l += 256) {
        uint32_t bb = l >> 4, cc = l & 15;
        sd[pad16(l)] = x[c0 + cc + (bb << 12)];
    }
    rowt[tid]       = (tid == 0) ? RMODP : Wfull[tid << 12];
    rowt[tid + 256] = Wfull[(uint32_t)(tid + 256) << 12];
    uint32_t cw[9];
    #pragma unroll
    for (int s = 0; s < 9; s++) cw[s] = Wfull[(1u << (12 + s)) + c0 + c];
    __syncthreads();

    // 4 radix-4 rounds: local stage pairs (0,1),(2,3),(4,5),(6,7)
    // w2j trick: rowt[2h+kk]*J = rowt[3h+kk]
    #pragma unroll
    for (int s = 0; s < 8; s += 2) {
        uint32_t h = 1u << s;
        #pragma unroll
        for (uint32_t m = 0; m < 8; m++) {
            uint32_t p = (rt << 3) + m;          // radix-4 unit 0..127
            uint32_t kk = p & (h - 1);
            uint32_t grp = p >> s;
            uint32_t r0 = (grp << (s + 2)) + kk;
            uint32_t w1  = montmul(rowt[h + kk], cw[s]);
            uint32_t w2  = montmul(rowt[2 * h + kk], cw[s + 1]);
            uint32_t w2j = montmul(rowt[3 * h + kk], cw[s + 1]);
            uint32_t i0 = pad16((r0 << 4) + c);
            uint32_t i1 = pad16(((r0 + h) << 4) + c);
            uint32_t i2 = pad16(((r0 + 2 * h) << 4) + c);
            uint32_t i3 = pad16(((r0 + 3 * h) << 4) + c);
            uint32_t a0 = sd[i0], a1 = sd[i1], a2 = sd[i2], a3 = sd[i3];
            uint32_t t1 = montmul(w1, a1), t3 = montmul(w1, a3);
            uint32_t b0 = addmod(a0, t1), b1 = submod(a0, t1);
            uint32_t b2 = addmod(a2, t3), b3 = submod(a2, t3);
            uint32_t u2 = montmul(w2, b2), u3 = montmul(w2j, b3);
            sd[i0] = addmod(b0, u2);
            sd[i2] = submod(b0, u2);
            sd[i1] = addmod(b1, u3);
            sd[i3] = submod(b1, u3);
        }
        __syncthreads();
    }
    // final radix-2 stage (local s=8, hb=256)
    #pragma unroll
    for (uint32_t m = 0; m < 16; m++) {
        uint32_t kk = (rt << 4) + m;       // 0..255
        uint32_t w = montmul(rowt[256 + kk], cw[8]);
        uint32_t i0 = pad16((kk << 4) + c), i1 = pad16(((kk + 256) << 4) + c);
        uint32_t u = sd[i0];
        uint32_t v = montmul(sd[i1], w);
        sd[i0] = addmod(u, v);
        sd[i1] = submod(u, v);
    }
    __syncthreads();

    // epilogue: final float values + fused commit partials
    float* xf = (float*)x;
    const float invp = (float)(1.0 / 2013265921.0);
    double a0 = 0.0, a1 = 0.0, a2 = 0.0;
    for (uint32_t l = tid; l < 8192; l += 256) {
        uint32_t bb = l >> 4, cc = l & 15;
        uint32_t idx = c0 + cc + (bb << 12);
        float fv = (float)sd[pad16(l)];
        xf[idx] = fv;
        float s = fv * invp;
        a0 += (double)(s * g[idx * 3 + 0]);
        a1 += (double)(s * g[idx * 3 + 1]);
        a2 += (double)(s * g[idx * 3 + 2]);
    }
    double v3[3] = {a0, a1, a2};
    #pragma unroll
    for (int kq = 0; kq < 3; kq++) {
        __syncthreads();
        red[tid] = v3[kq];
        __syncthreads();
        for (int off = 128; off > 0; off >>= 1) {
            if (tid < off) red[tid] += red[tid + off];
            __syncthreads();
        }
        if (tid == 0) partials[((size_t)poly * 256 + c0_idx) * 3 + kq] = red[0];
    }
}

// ---------- final commit reduce: 8 polys x 256 blocks x 3 comps -> 24 floats ----------
__global__ void reduce_commits_kernel(const double* __restrict__ partials, float* __restrict__ outf) {
    __shared__ double red[256];
    int t = threadIdx.x;
    for (int k = 0; k < 24; k++) {
        int p = k / 3, cc = k % 3;
        red[t] = partials[((size_t)p * 256 + t) * 3 + cc];
        __syncthreads();
        for (int off = 128; off > 0; off >>= 1) {
            if (t < off) red[t] += red[t + off];
            __syncthreads();
        }
        if (t == 0) outf[k] = (float)red[0];
        __syncthreads();
    }
}

extern "C" void kernel_launch(void* const* d_in, const int* in_sizes, int n_in,
                              void* d_out, int out_size, void* d_ws, size_t ws_size,
                              hipStream_t stream) {
    const int* wl = (const int*)d_in[0];
    const int* wr = (const int*)d_in[1];
    const int* wo = (const int*)d_in[2];
    const int* w4 = (const int*)d_in[3];
    const int* t1 = (const int*)d_in[4];
    const int* t2 = (const int*)d_in[5];
    const int* t3 = (const int*)d_in[6];
    const int* t4 = (const int*)d_in[7];
    const int* q  = (const int*)d_in[8];
    const float* g = (const float*)d_in[9];
    const int* zp = (const int*)d_in[10];

    char* ws = (char*)d_ws;
    uint32_t* Wfull  = (uint32_t*)(ws);                       // 8 MB
    uint32_t* tcomp  = (uint32_t*)(ws + (8ull  << 20));       // 8 MB
    uint32_t* fcomp  = (uint32_t*)(ws + (16ull << 20));       // 8 MB
    uint32_t* h1     = (uint32_t*)(ws + (24ull << 20));       // 8 MB
    uint32_t* h2     = (uint32_t*)(ws + (32ull << 20));       // 8 MB
    // small buffers at 64 KiB-aligned offsets
    unsigned int* hist    = (unsigned int*)(ws + (40ull << 20));                  // 32 KB
    unsigned int* basearr = (unsigned int*)(ws + (40ull << 20) + (64u  << 10));   // 32 KB+4
    unsigned int* fcursor = (unsigned int*)(ws + (40ull << 20) + (128u << 10));   // 32 KB
    uint32_t*     tA      = (uint32_t*)   (ws + (40ull << 20) + (200u << 10));    // 4 KB
    uint32_t*     tB      = (uint32_t*)   (ws + (40ull << 20) + (208u << 10));    // 4 KB
    unsigned int* hist64  = (unsigned int*)(ws + (40ull << 20) + (216u << 10));   // 256 B
    unsigned int* cbase   = (unsigned int*)(ws + (40ull << 20) + (224u << 10));   // 260 B
    unsigned int* ccursor = (unsigned int*)(ws + (40ull << 20) + (232u << 10));   // 256 B
    double*       partials = (double*)    (ws + (40ull << 20) + (256u << 10));    // 48 KB (8-aligned)

    float* outf = (float*)d_out;
    uint32_t* outpolys = (uint32_t*)outf + 24;                      // 8*N, final floats
    uint32_t* barr1 = (uint32_t*)outf + 1024;                       // 16 MB scratch (pre-NTT)
    uint32_t* barr2 = (uint32_t*)outf + 1024 + (5u << 20);          // 16 MB scratch (pre-NTT)

    hipMemsetAsync(hist, 0, NBUCK * sizeof(unsigned int), stream);
    hipMemsetAsync(hist64, 0, 64 * sizeof(unsigned int), stream);

    twiddle_ab_kernel<<<4, 256, 0, stream>>>(tA, tB);
    twiddle_fill_kernel<<<NN / 256, 256, 0, stream>>>(tA, tB, Wfull);

    compress_kernel<<<2048, 256, 0, stream>>>(wl, wr, wo, w4, t1, t2, t3, t4, q, zp,
                                              tcomp, fcomp, hist64);
    scan64_kernel<<<1, 64, 0, stream>>>(hist64, cbase, ccursor);
    pass1_kernel<<<1024, 256, 0, stream>>>(tcomp, fcomp, ccursor, barr1);
    fine_hist_kernel<<<dim3(16, 64), 256, 0, stream>>>(barr1, cbase, hist);
    scan_kernel<<<1, 256, 0, stream>>>(hist, basearr, fcursor);
    pass2_kernel<<<dim3(16, 64), 256, 0, stream>>>(barr1, cbase, fcursor, barr2);
    bucket_sort_kernel<<<NBUCK, 256, 0, stream>>>(barr2, basearr, h1, h2);

    SrcPtrs sp;
    sp.p[0] = (const uint32_t*)wl;
    sp.p[1] = (const uint32_t*)wr;
    sp.p[2] = (const uint32_t*)wo;
    sp.p[3] = (const uint32_t*)w4;
    sp.p[4] = tcomp;
    sp.p[5] = fcomp;
    sp.p[6] = h1;
    sp.p[7] = h2;
    bitrev_kernel<<<dim3(512, 8), 256, 0, stream>>>(sp, outpolys);
    ntt_phase1_kernel<<<dim3(512, 8), 256, 0, stream>>>(outpolys, Wfull);
    ntt_phase2_kernel<<<2048, 256, 0, stream>>>(outpolys, Wfull, g, partials);

    reduce_commits_kernel<<<1, 256, 0, stream>>>(partials, outf);
}